// Round 2
// baseline (3494.659 us; speedup 1.0000x reference)
//
#include <hip/hip_runtime.h>
#include <hip/hip_bf16.h>

#define BB 128
#define LL 512
#define DW 256
#define DP 64
#define NF 512
#define DD 384       // D = DW + 2*DP
#define DWIN 1152    // 3*D
#define RR 512       // nr

// ---------- Kernel A: v1[b,d] = sum_e We1[d,e]*e1[b,e]; v2 likewise ----------
__global__ void k_ve(const float* __restrict__ We1, const float* __restrict__ We2,
                     const float* __restrict__ e1, const float* __restrict__ e2,
                     float* __restrict__ v1, float* __restrict__ v2) {
    int b = blockIdx.x;
    int d = threadIdx.x; // 256
    __shared__ float s1[DW], s2[DW];
    s1[d] = e1[b * DW + d];
    s2[d] = e2[b * DW + d];
    __syncthreads();
    float a1 = 0.f, a2 = 0.f;
    for (int e = 0; e < DW; ++e) {
        a1 += We1[d * DW + e] * s1[e];
        a2 += We2[d * DW + e] * s2[e];
    }
    v1[b * DW + d] = a1;
    v2[b * DW + d] = a2;
}

// ---------- Kernel B: A1[b,l] = sum_d x[b,l,d]*v1[b,d]; A2 likewise ----------
__global__ void k_logits(const float* __restrict__ x,
                         const float* __restrict__ v1, const float* __restrict__ v2,
                         float* __restrict__ A1, float* __restrict__ A2) {
    int bl = blockIdx.x;
    int b = bl / LL;
    int t = threadIdx.x; // 256
    float xv = x[(size_t)bl * DW + t];
    float p1 = xv * v1[b * DW + t];
    float p2 = xv * v2[b * DW + t];
    for (int off = 32; off; off >>= 1) {
        p1 += __shfl_down(p1, off);
        p2 += __shfl_down(p2, off);
    }
    __shared__ float r1[4], r2[4];
    int w = t >> 6;
    if ((t & 63) == 0) { r1[w] = p1; r2[w] = p2; }
    __syncthreads();
    if (t == 0) {
        A1[bl] = r1[0] + r1[1] + r1[2] + r1[3];
        A2[bl] = r2[0] + r2[1] + r2[2] + r2[3];
    }
}

// ---------- Kernel C: alpha = 0.5*(softmax(A1) + softmax(A2)) over L ----------
__global__ void k_alpha(const float* __restrict__ A1, const float* __restrict__ A2,
                        float* __restrict__ alpha) {
    int b = blockIdx.x;
    int l = threadIdx.x; // 512
    __shared__ float s[LL];
    float a1 = A1[b * LL + l], a2 = A2[b * LL + l];

    s[l] = a1; __syncthreads();
    for (int st = 256; st; st >>= 1) { if (l < st) s[l] = fmaxf(s[l], s[l + st]); __syncthreads(); }
    float m1 = s[0]; __syncthreads();
    float e1x = expf(a1 - m1);
    s[l] = e1x; __syncthreads();
    for (int st = 256; st; st >>= 1) { if (l < st) s[l] += s[l + st]; __syncthreads(); }
    float d1 = s[0]; __syncthreads();

    s[l] = a2; __syncthreads();
    for (int st = 256; st; st >>= 1) { if (l < st) s[l] = fmaxf(s[l], s[l + st]); __syncthreads(); }
    float m2 = s[0]; __syncthreads();
    float e2x = expf(a2 - m2);
    s[l] = e2x; __syncthreads();
    for (int st = 256; st; st >>= 1) { if (l < st) s[l] += s[l + st]; __syncthreads(); }
    float d2 = s[0];

    alpha[b * LL + l] = 0.5f * (e1x / d1 + e2x / d2);
}

// ---------- Kernel E: W2[f,r] = sum_t U[f,t]*rel_w[r,t] ----------
__global__ void k_w2(const float* __restrict__ U, const float* __restrict__ relw,
                     float* __restrict__ W2) {
    __shared__ float As[16][65], Bs[16][65];
    int f0 = blockIdx.y * 64, r0 = blockIdx.x * 64;
    int tid = threadIdx.x;
    int ty = tid >> 4, tx = tid & 15;
    float acc[4][4] = {};
    for (int k0 = 0; k0 < NF; k0 += 16) {
        for (int i = 0; i < 4; ++i) {
            int lin = tid + 256 * i;
            int kk = lin & 15, mm = lin >> 4;
            As[kk][mm] = U[(f0 + mm) * NF + k0 + kk];
            Bs[kk][mm] = relw[(r0 + mm) * NF + k0 + kk];
        }
        __syncthreads();
        for (int kk = 0; kk < 16; ++kk) {
            float av[4], bv[4];
            for (int i = 0; i < 4; ++i) av[i] = As[kk][ty * 4 + i];
            for (int j = 0; j < 4; ++j) bv[j] = Bs[kk][tx * 4 + j];
            for (int i = 0; i < 4; ++i)
                for (int j = 0; j < 4; ++j) acc[i][j] += av[i] * bv[j];
        }
        __syncthreads();
    }
    for (int i = 0; i < 4; ++i)
        for (int j = 0; j < 4; ++j)
            W2[(f0 + ty * 4 + i) * RR + r0 + tx * 4 + j] = acc[i][j];
}

// ---------- Kernel D: conv[b,f,l] = tanh(alpha[b,l]*S[b,f,l] + conv_b[f]) ----------
// S[b,f,l] = sum_k w_concat[b,l,k]*conv_w[f,k], w_concat gathered from x/posVec
// Output stored as bf16 (keeps workspace under 256 MiB).
__global__ void k_conv(const float* __restrict__ x, const float* __restrict__ posVec,
                       const float* __restrict__ conv_w, const float* __restrict__ conv_b,
                       const float* __restrict__ alpha, __hip_bfloat16* __restrict__ conv) {
    int b = blockIdx.z;
    int f0 = blockIdx.y * 64, l0 = blockIdx.x * 64;
    __shared__ float As[16][65], Bs[16][65];
    int tid = threadIdx.x, ty = tid >> 4, tx = tid & 15;
    float acc[4][4] = {};
    for (int k0 = 0; k0 < DWIN; k0 += 16) {
        for (int i = 0; i < 4; ++i) {
            int lin = tid + 256 * i;
            int kk = lin & 15, mm = lin >> 4;
            As[kk][mm] = conv_w[(f0 + mm) * DWIN + k0 + kk];
            int k = k0 + kk;
            int j = k / DD, d = k - j * DD;
            int row = l0 + mm - 1 + j;
            float val = 0.f;
            if (row >= 0 && row < LL) {
                val = (d < DW) ? x[((size_t)b * LL + row) * DW + d]
                               : posVec[((size_t)b * LL + row) * (2 * DP) + (d - DW)];
            }
            Bs[kk][mm] = val;
        }
        __syncthreads();
        for (int kk = 0; kk < 16; ++kk) {
            float av[4], bv[4];
            for (int i = 0; i < 4; ++i) av[i] = As[kk][ty * 4 + i];
            for (int j = 0; j < 4; ++j) bv[j] = Bs[kk][tx * 4 + j];
            for (int i = 0; i < 4; ++i)
                for (int j = 0; j < 4; ++j) acc[i][j] += av[i] * bv[j];
        }
        __syncthreads();
    }
    for (int i = 0; i < 4; ++i) {
        int f = f0 + ty * 4 + i;
        float bias = conv_b[f];
        for (int j = 0; j < 4; ++j) {
            int l = l0 + tx * 4 + j;
            float pre = alpha[b * LL + l] * acc[i][j] + bias;
            conv[((size_t)b * NF + f) * LL + l] = __float2bfloat16(tanhf(pre));
        }
    }
}

// ---------- Kernel F: G[b,l,r] = sum_f conv[b,f,l]*W2[f,r] ----------
__global__ void k_g(const __hip_bfloat16* __restrict__ conv, const float* __restrict__ W2,
                    float* __restrict__ G) {
    int b = blockIdx.z;
    int l0 = blockIdx.y * 64, r0 = blockIdx.x * 64;
    __shared__ float As[16][65], Bs[16][65];
    int tid = threadIdx.x, ty = tid >> 4, tx = tid & 15;
    float acc[4][4] = {};
    const __hip_bfloat16* convb = conv + (size_t)b * NF * LL;
    for (int f0 = 0; f0 < NF; f0 += 16) {
        for (int i = 0; i < 4; ++i) {
            int lin = tid + 256 * i;
            int ll = lin & 63, kf = lin >> 6;
            As[kf][ll] = __bfloat162float(convb[(f0 + kf) * LL + l0 + ll]);
            Bs[kf][ll] = W2[(f0 + kf) * RR + r0 + ll];
        }
        __syncthreads();
        for (int kk = 0; kk < 16; ++kk) {
            float av[4], bv[4];
            for (int i = 0; i < 4; ++i) av[i] = As[kk][ty * 4 + i];
            for (int j = 0; j < 4; ++j) bv[j] = Bs[kk][tx * 4 + j];
            for (int i = 0; i < 4; ++i)
                for (int j = 0; j < 4; ++j) acc[i][j] += av[i] * bv[j];
        }
        __syncthreads();
    }
    for (int i = 0; i < 4; ++i) {
        int l = l0 + ty * 4 + i;
        for (int j = 0; j < 4; ++j) {
            int r = r0 + tx * 4 + j;
            G[((size_t)b * LL + l) * RR + r] = acc[i][j];
        }
    }
}

// ---------- Kernel G: softmax over l (axis=1) of G, in place ----------
__global__ void k_apsm(float* __restrict__ G) {
    int b = blockIdx.y;
    int r = blockIdx.x * 256 + threadIdx.x;
    float* col = G + (size_t)b * LL * RR + r;
    float m = -1e30f;
    for (int l = 0; l < LL; ++l) m = fmaxf(m, col[(size_t)l * RR]);
    float s = 0.f;
    for (int l = 0; l < LL; ++l) s += expf(col[(size_t)l * RR] - m);
    float inv = 1.f / s;
    for (int l = 0; l < LL; ++l) col[(size_t)l * RR] = expf(col[(size_t)l * RR] - m) * inv;
}

// ---------- Kernel H: wo[b,f] = relu(max_r sum_l conv[b,f,l]*AP[b,l,r]) ----------
__global__ void k_wo(const __hip_bfloat16* __restrict__ conv, const float* __restrict__ AP,
                     float* __restrict__ wo) {
    int b = blockIdx.z;
    int f0 = blockIdx.y * 64, r0 = blockIdx.x * 64;
    __shared__ float As[16][65], Bs[16][65];
    int tid = threadIdx.x, ty = tid >> 4, tx = tid & 15;
    float acc[4][4] = {};
    const __hip_bfloat16* convb = conv + (size_t)b * NF * LL;
    const float* apb = AP + (size_t)b * LL * RR;
    for (int l0 = 0; l0 < LL; l0 += 16) {
        for (int i = 0; i < 4; ++i) {
            int lin = tid + 256 * i;
            int kk = lin & 15, mm = lin >> 4;
            As[kk][mm] = __bfloat162float(convb[(f0 + mm) * LL + l0 + kk]);
            int rr2 = lin & 63, kl = lin >> 6;
            Bs[kl][rr2] = apb[(size_t)(l0 + kl) * RR + r0 + rr2];
        }
        __syncthreads();
        for (int kk = 0; kk < 16; ++kk) {
            float av[4], bv[4];
            for (int i = 0; i < 4; ++i) av[i] = As[kk][ty * 4 + i];
            for (int j = 0; j < 4; ++j) bv[j] = Bs[kk][tx * 4 + j];
            for (int i = 0; i < 4; ++i)
                for (int j = 0; j < 4; ++j) acc[i][j] += av[i] * bv[j];
        }
        __syncthreads();
    }
    for (int i = 0; i < 4; ++i) {
        float m = fmaxf(fmaxf(acc[i][0], acc[i][1]), fmaxf(acc[i][2], acc[i][3]));
        if (m > 0.f) {
            atomicMax((int*)&wo[b * NF + f0 + ty * 4 + i], __float_as_int(m));
        }
    }
}

extern "C" void kernel_launch(void* const* d_in, const int* in_sizes, int n_in,
                              void* d_out, int out_size, void* d_ws, size_t ws_size,
                              hipStream_t stream) {
    const float* x      = (const float*)d_in[0];
    const float* e1     = (const float*)d_in[1];
    const float* e2     = (const float*)d_in[2];
    const float* posVec = (const float*)d_in[3];
    const float* We1    = (const float*)d_in[4];
    const float* We2    = (const float*)d_in[5];
    const float* U      = (const float*)d_in[6];
    const float* conv_w = (const float*)d_in[7];
    const float* conv_b = (const float*)d_in[8];
    const float* rel_w  = (const float*)d_in[9];
    float* out = (float*)d_out;

    // workspace layout (bytes):
    //   conv  bf16  B*NF*LL*2      =  67,108,864
    //   G     f32   B*LL*RR*4      = 134,217,728
    //   W2    f32   NF*RR*4        =   1,048,576
    //   v1,v2 f32   2*B*DW*4       =     262,144
    //   A1,A2,alpha f32 3*B*LL*4   =     786,432
    //   total                      = 203,423,744  (< 256 MiB)
    __hip_bfloat16* conv = (__hip_bfloat16*)d_ws;
    float* G     = (float*)((char*)d_ws + (size_t)BB * NF * LL * sizeof(__hip_bfloat16));
    float* W2    = G + (size_t)BB * LL * RR;
    float* v1    = W2 + NF * RR;
    float* v2    = v1 + BB * DW;
    float* A1    = v2 + BB * DW;
    float* A2    = A1 + BB * LL;
    float* alpha = A2 + BB * LL;

    k_ve<<<BB, DW, 0, stream>>>(We1, We2, e1, e2, v1, v2);
    k_logits<<<BB * LL, DW, 0, stream>>>(x, v1, v2, A1, A2);
    k_alpha<<<BB, LL, 0, stream>>>(A1, A2, alpha);
    k_w2<<<dim3(RR / 64, NF / 64), 256, 0, stream>>>(U, rel_w, W2);
    k_conv<<<dim3(LL / 64, NF / 64, BB), 256, 0, stream>>>(x, posVec, conv_w, conv_b, alpha, conv);
    k_g<<<dim3(RR / 64, LL / 64, BB), 256, 0, stream>>>(conv, W2, G);
    k_apsm<<<dim3(RR / 256, BB), 256, 0, stream>>>(G);
    hipMemsetAsync(d_out, 0, (size_t)BB * NF * sizeof(float), stream);
    k_wo<<<dim3(RR / 64, NF / 64, BB), 256, 0, stream>>>(conv, G, out);
    hipMemcpyAsync(out + BB * NF, rel_w, (size_t)NF * RR * sizeof(float),
                   hipMemcpyDeviceToDevice, stream);
}

// Round 3
// 827.818 us; speedup vs baseline: 4.2215x; 4.2215x over previous
//
#include <hip/hip_runtime.h>
#include <hip/hip_bf16.h>

#define BB 128
#define LL 512
#define DW 256
#define DP 64
#define NF 512
#define DD 384       // D = DW + 2*DP
#define DWIN 1152    // 3*D
#define RR 512       // nr

typedef __attribute__((ext_vector_type(8))) short short8;
typedef __attribute__((ext_vector_type(4))) float f32x4;

__device__ inline short f2b(float v) {
    __hip_bfloat16 h = __float2bfloat16(v);
    return *reinterpret_cast<short*>(&h);
}
__device__ inline float b2f(short s) {
    unsigned u = ((unsigned)(unsigned short)s) << 16;
    return __uint_as_float(u);
}

// ---------- small kernels (unchanged, fp32-exact path for alpha) ----------
__global__ void k_ve(const float* __restrict__ We1, const float* __restrict__ We2,
                     const float* __restrict__ e1, const float* __restrict__ e2,
                     float* __restrict__ v1, float* __restrict__ v2) {
    int b = blockIdx.x;
    int d = threadIdx.x; // 256
    __shared__ float s1[DW], s2[DW];
    s1[d] = e1[b * DW + d];
    s2[d] = e2[b * DW + d];
    __syncthreads();
    float a1 = 0.f, a2 = 0.f;
    for (int e = 0; e < DW; ++e) {
        a1 += We1[d * DW + e] * s1[e];
        a2 += We2[d * DW + e] * s2[e];
    }
    v1[b * DW + d] = a1;
    v2[b * DW + d] = a2;
}

__global__ void k_logits(const float* __restrict__ x,
                         const float* __restrict__ v1, const float* __restrict__ v2,
                         float* __restrict__ A1, float* __restrict__ A2) {
    int bl = blockIdx.x;
    int b = bl / LL;
    int t = threadIdx.x; // 256
    float xv = x[(size_t)bl * DW + t];
    float p1 = xv * v1[b * DW + t];
    float p2 = xv * v2[b * DW + t];
    for (int off = 32; off; off >>= 1) {
        p1 += __shfl_down(p1, off);
        p2 += __shfl_down(p2, off);
    }
    __shared__ float r1[4], r2[4];
    int w = t >> 6;
    if ((t & 63) == 0) { r1[w] = p1; r2[w] = p2; }
    __syncthreads();
    if (t == 0) {
        A1[bl] = r1[0] + r1[1] + r1[2] + r1[3];
        A2[bl] = r2[0] + r2[1] + r2[2] + r2[3];
    }
}

__global__ void k_alpha(const float* __restrict__ A1, const float* __restrict__ A2,
                        float* __restrict__ alpha) {
    int b = blockIdx.x;
    int l = threadIdx.x; // 512
    __shared__ float s[LL];
    float a1 = A1[b * LL + l], a2 = A2[b * LL + l];

    s[l] = a1; __syncthreads();
    for (int st = 256; st; st >>= 1) { if (l < st) s[l] = fmaxf(s[l], s[l + st]); __syncthreads(); }
    float m1 = s[0]; __syncthreads();
    float e1x = expf(a1 - m1);
    s[l] = e1x; __syncthreads();
    for (int st = 256; st; st >>= 1) { if (l < st) s[l] += s[l + st]; __syncthreads(); }
    float d1 = s[0]; __syncthreads();

    s[l] = a2; __syncthreads();
    for (int st = 256; st; st >>= 1) { if (l < st) s[l] = fmaxf(s[l], s[l + st]); __syncthreads(); }
    float m2 = s[0]; __syncthreads();
    float e2x = expf(a2 - m2);
    s[l] = e2x; __syncthreads();
    for (int st = 256; st; st >>= 1) { if (l < st) s[l] += s[l + st]; __syncthreads(); }
    float d2 = s[0];

    alpha[b * LL + l] = 0.5f * (e1x / d1 + e2x / d2);
}

// ---------- packing ----------
__global__ void k_pack_px(const float* __restrict__ x, const float* __restrict__ pv,
                          short* __restrict__ px) {
    int idx = blockIdx.x * 256 + threadIdx.x;   // 128*512*384 = 25,165,824
    int d = idx % DD;
    int bl = idx / DD;
    float v = (d < DW) ? x[(size_t)bl * DW + d] : pv[(size_t)bl * (2 * DP) + (d - DW)];
    px[idx] = f2b(v);
}

__global__ void k_pack_w(const float* __restrict__ cw, short* __restrict__ cwb) {
    int idx = blockIdx.x * 256 + threadIdx.x;   // 512*1152 = 589,824
    cwb[idx] = f2b(cw[idx]);
}

// ---------- W2t[r][f] = sum_t rel_w[r,t]*U[f,t], split hi/lo bf16 ----------
__global__ void k_w2t(const float* __restrict__ U, const float* __restrict__ relw,
                      short* __restrict__ Qh, short* __restrict__ Ql) {
    __shared__ float As[16][65], Bs[16][65];
    int r0 = blockIdx.y * 64, f0 = blockIdx.x * 64;
    int tid = threadIdx.x, ty = tid >> 4, tx = tid & 15;
    float acc[4][4] = {};
    for (int k0 = 0; k0 < NF; k0 += 16) {
        for (int i = 0; i < 4; ++i) {
            int lin = tid + 256 * i;
            int kk = lin & 15, mm = lin >> 4;
            As[kk][mm] = relw[(r0 + mm) * NF + k0 + kk];
            Bs[kk][mm] = U[(f0 + mm) * NF + k0 + kk];
        }
        __syncthreads();
        for (int kk = 0; kk < 16; ++kk) {
            float av[4], bv[4];
            for (int i = 0; i < 4; ++i) av[i] = As[kk][ty * 4 + i];
            for (int j = 0; j < 4; ++j) bv[j] = Bs[kk][tx * 4 + j];
            for (int i = 0; i < 4; ++i)
                for (int j = 0; j < 4; ++j) acc[i][j] += av[i] * bv[j];
        }
        __syncthreads();
    }
    for (int i = 0; i < 4; ++i)
        for (int j = 0; j < 4; ++j) {
            float vv = acc[i][j];
            short hi = f2b(vv);
            size_t o = (size_t)(r0 + ty * 4 + i) * NF + f0 + tx * 4 + j;
            Qh[o] = hi;
            Ql[o] = f2b(vv - b2f(hi));
        }
}

// ---------- conv MFMA: D[m=l, n=f] = sum_k pxwin[l,k]*conv_w[f,k] ----------
// epilogue: conv_lf[b,l,f] = bf16(tanh(alpha[b,l]*acc + conv_b[f]))
__global__ __launch_bounds__(256) void k_conv_mfma(
    const short* __restrict__ px, const short* __restrict__ cw,
    const float* __restrict__ conv_b, const float* __restrict__ alpha,
    short* __restrict__ conv_lf) {
    int b = blockIdx.z;
    int l0 = blockIdx.y * 128;
    int f0 = blockIdx.x * 128;
    int tid = threadIdx.x;
    int lane = tid & 63, w = tid >> 6;
    int wm = w >> 1, wn = w & 1;
    int lr = lane & 15, lg = lane >> 4;

    __shared__ short As[128][40];   // A[l][k], row stride 80B (2-way free)
    __shared__ short Bs[128][40];   // B[f][k]

    f32x4 acc[4][4];
    for (int i = 0; i < 4; ++i)
        for (int j = 0; j < 4; ++j) acc[i][j] = (f32x4){0.f, 0.f, 0.f, 0.f};

    for (int kb = 0; kb < 36; ++kb) {
        int k0 = kb * 32;
        int j = k0 / DD;          // 0..2 (32 | 384 so no boundary crossing)
        int d0 = k0 - j * DD;
#pragma unroll
        for (int i = 0; i < 2; ++i) {
            int lin = tid + 256 * i;       // 0..511
            int row = lin >> 2;            // 0..127
            int q = lin & 3;
            int gl = l0 + row - 1 + j;
            short8 v = (short8){0, 0, 0, 0, 0, 0, 0, 0};
            if (gl >= 0 && gl < LL)
                v = *(const short8*)(px + ((size_t)b * LL + gl) * DD + d0 + q * 8);
            *(short8*)(&As[row][q * 8]) = v;
            short8 u = *(const short8*)(cw + (size_t)(f0 + row) * DWIN + k0 + q * 8);
            *(short8*)(&Bs[row][q * 8]) = u;
        }
        __syncthreads();
        short8 af[4], bf[4];
#pragma unroll
        for (int mi = 0; mi < 4; ++mi)
            af[mi] = *(const short8*)(&As[wm * 64 + mi * 16 + lr][lg * 8]);
#pragma unroll
        for (int ni = 0; ni < 4; ++ni)
            bf[ni] = *(const short8*)(&Bs[wn * 64 + ni * 16 + lr][lg * 8]);
#pragma unroll
        for (int mi = 0; mi < 4; ++mi)
#pragma unroll
            for (int ni = 0; ni < 4; ++ni)
                acc[mi][ni] = __builtin_amdgcn_mfma_f32_16x16x32_bf16(
                    af[mi], bf[ni], acc[mi][ni], 0, 0, 0);
        __syncthreads();
    }

    int lbase = l0 + wm * 64, fbase = f0 + wn * 64;
#pragma unroll
    for (int mi = 0; mi < 4; ++mi) {
        f32x4 av = *(const f32x4*)(alpha + (size_t)b * LL + lbase + mi * 16 + lg * 4);
#pragma unroll
        for (int ni = 0; ni < 4; ++ni) {
            int f = fbase + ni * 16 + lr;
            float bias = conv_b[f];
#pragma unroll
            for (int r = 0; r < 4; ++r) {
                int l = lbase + mi * 16 + lg * 4 + r;
                float val = tanhf(av[r] * acc[mi][ni][r] + bias);
                conv_lf[((size_t)b * LL + l) * NF + f] = f2b(val);
            }
        }
    }
}

// ---------- transpose conv_lf[b,l,f] -> conv_fl[b,f,l] (64x64 tiles) ----------
__global__ __launch_bounds__(256) void k_transpose(const short* __restrict__ src,
                                                   short* __restrict__ dst) {
    int b = blockIdx.z;
    int l0 = blockIdx.y * 64, f0 = blockIdx.x * 64;
    __shared__ short T[64][72];    // [f][l], row stride 144B
    int tid = threadIdx.x;
#pragma unroll
    for (int i = 0; i < 2; ++i) {
        int lin = tid + 256 * i;
        int lrow = lin & 63, q = lin >> 6;   // q 0..7
        short8 v = *(const short8*)(src + ((size_t)b * LL + l0 + lrow) * NF + f0 + q * 8);
#pragma unroll
        for (int jj = 0; jj < 8; ++jj) T[q * 8 + jj][lrow] = v[jj];
    }
    __syncthreads();
#pragma unroll
    for (int i = 0; i < 2; ++i) {
        int lin = tid + 256 * i;
        int frow = lin & 63, q = lin >> 6;
        short8 v = *(const short8*)(&T[frow][q * 8]);
        *(short8*)(dst + ((size_t)b * NF + f0 + frow) * LL + l0 + q * 8) = v;
    }
}

// ---------- flash attentive pooling ----------
// Per (b, 32-r tile): S[r,l] = (Qh+Ql)[r,:]·K[l,:];  online softmax over l;
// O[r,f] += P·V;  epilogue: out[b,f] = atomicMax over r of O/sum  (relu via init-0)
__global__ __launch_bounds__(256) void k_flash(
    const short* __restrict__ Qh, const short* __restrict__ Ql,
    const short* __restrict__ Km,   // conv_lf [b][l][f]
    const short* __restrict__ Vm,   // conv_fl [b][f][l]
    float* __restrict__ out) {
    int b = blockIdx.y;
    int r0 = blockIdx.x * 32;
    int tid = threadIdx.x, lane = tid & 63, w = tid >> 6;
    int lr = lane & 15, lg = lane >> 4;

    __shared__ short Qs[32][520];   // Q-hi tile, stride 1040B
    __shared__ float Sb[32][65];
    __shared__ short Pl[32][72];    // P bf16, stride 144B
    __shared__ float mrow[32], srow[32], frow[32];

#pragma unroll
    for (int i = 0; i < 8; ++i) {
        int lin = tid + 256 * i;           // 0..2047
        int row = lin >> 6, q = lin & 63;
        *(short8*)(&Qs[row][q * 8]) = *(const short8*)(Qh + (size_t)(r0 + row) * NF + q * 8);
    }
    if (tid < 32) { mrow[tid] = -1e30f; srow[tid] = 0.f; }
    __syncthreads();

    const short* Kb = Km + (size_t)b * LL * NF;
    const short* Vb = Vm + (size_t)b * NF * LL;

    f32x4 acc[2][8];
#pragma unroll
    for (int mi = 0; mi < 2; ++mi)
#pragma unroll
        for (int ni = 0; ni < 8; ++ni) acc[mi][ni] = (f32x4){0.f, 0.f, 0.f, 0.f};

    const float LOG2E = 1.4426950408889634f;
    for (int it = 0; it < 8; ++it) {
        int l0 = it * 64;
        // phase 1: scores; wave w computes cols l0+w*16 .. +15
        f32x4 sacc[2];
        sacc[0] = (f32x4){0.f, 0.f, 0.f, 0.f};
        sacc[1] = (f32x4){0.f, 0.f, 0.f, 0.f};
        int lc = l0 + w * 16 + lr;
        for (int ks = 0; ks < 16; ++ks) {
            int kb2 = ks * 32;
            short8 bk = *(const short8*)(Kb + (size_t)lc * NF + kb2 + lg * 8);
#pragma unroll
            for (int mi = 0; mi < 2; ++mi) {
                short8 ah = *(const short8*)(&Qs[mi * 16 + lr][kb2 + lg * 8]);
                sacc[mi] = __builtin_amdgcn_mfma_f32_16x16x32_bf16(ah, bk, sacc[mi], 0, 0, 0);
                short8 al = *(const short8*)(Ql + (size_t)(r0 + mi * 16 + lr) * NF + kb2 + lg * 8);
                sacc[mi] = __builtin_amdgcn_mfma_f32_16x16x32_bf16(al, bk, sacc[mi], 0, 0, 0);
            }
        }
#pragma unroll
        for (int mi = 0; mi < 2; ++mi)
#pragma unroll
            for (int r = 0; r < 4; ++r)
                Sb[mi * 16 + lg * 4 + r][w * 16 + lr] = sacc[mi][r];
        __syncthreads();

        // phase 2: online softmax update (8 threads per row)
        {
            int row = tid >> 3, sub = tid & 7;
            float om = mrow[row];
            float v[8];
#pragma unroll
            for (int jj = 0; jj < 8; ++jj) v[jj] = Sb[row][sub * 8 + jj];
            float lm = v[0];
#pragma unroll
            for (int jj = 1; jj < 8; ++jj) lm = fmaxf(lm, v[jj]);
            lm = fmaxf(lm, __shfl_xor(lm, 1));
            lm = fmaxf(lm, __shfl_xor(lm, 2));
            lm = fmaxf(lm, __shfl_xor(lm, 4));
            float nm = fmaxf(om, lm);
            float ps = 0.f;
#pragma unroll
            for (int jj = 0; jj < 8; ++jj) {
                float p = exp2f((v[jj] - nm) * LOG2E);
                ps += p;
                Pl[row][sub * 8 + jj] = f2b(p);
            }
            ps += __shfl_xor(ps, 1);
            ps += __shfl_xor(ps, 2);
            ps += __shfl_xor(ps, 4);
            float fac = exp2f((om - nm) * LOG2E);
            if (sub == 0) {
                mrow[row] = nm;
                srow[row] = srow[row] * fac + ps;
                frow[row] = fac;
            }
        }
        __syncthreads();

        // phase 3: rescale + PV; wave w owns f-chunk w*128
        {
            int fbase = w * 128;
#pragma unroll
            for (int mi = 0; mi < 2; ++mi) {
                f32x4 fv = *(const f32x4*)(&frow[mi * 16 + lg * 4]);
#pragma unroll
                for (int ni = 0; ni < 8; ++ni)
#pragma unroll
                    for (int r = 0; r < 4; ++r) acc[mi][ni][r] *= fv[r];
            }
#pragma unroll
            for (int kk = 0; kk < 2; ++kk) {
                short8 pa0 = *(const short8*)(&Pl[lr][kk * 32 + lg * 8]);
                short8 pa1 = *(const short8*)(&Pl[16 + lr][kk * 32 + lg * 8]);
#pragma unroll
                for (int ni = 0; ni < 8; ++ni) {
                    short8 bv = *(const short8*)(Vb + (size_t)(fbase + ni * 16 + lr) * LL + l0 + kk * 32 + lg * 8);
                    acc[0][ni] = __builtin_amdgcn_mfma_f32_16x16x32_bf16(pa0, bv, acc[0][ni], 0, 0, 0);
                    acc[1][ni] = __builtin_amdgcn_mfma_f32_16x16x32_bf16(pa1, bv, acc[1][ni], 0, 0, 0);
                }
            }
        }
        __syncthreads();
    }

    // epilogue: divide by row-sum, column max over the 32 rows, relu+atomicMax
    int fbase = w * 128;
    f32x4 inv[2];
#pragma unroll
    for (int mi = 0; mi < 2; ++mi) {
        f32x4 sv = *(const f32x4*)(&srow[mi * 16 + lg * 4]);
#pragma unroll
        for (int r = 0; r < 4; ++r) inv[mi][r] = 1.f / sv[r];
    }
#pragma unroll
    for (int ni = 0; ni < 8; ++ni) {
        float cm = -1e30f;
#pragma unroll
        for (int mi = 0; mi < 2; ++mi)
#pragma unroll
            for (int r = 0; r < 4; ++r)
                cm = fmaxf(cm, acc[mi][ni][r] * inv[mi][r]);
        cm = fmaxf(cm, __shfl_xor(cm, 16));
        cm = fmaxf(cm, __shfl_xor(cm, 32));
        if (lg == 0 && cm > 0.f)
            atomicMax((int*)&out[(size_t)b * NF + fbase + ni * 16 + lr], __float_as_int(cm));
    }
}

extern "C" void kernel_launch(void* const* d_in, const int* in_sizes, int n_in,
                              void* d_out, int out_size, void* d_ws, size_t ws_size,
                              hipStream_t stream) {
    const float* x      = (const float*)d_in[0];
    const float* e1     = (const float*)d_in[1];
    const float* e2     = (const float*)d_in[2];
    const float* posVec = (const float*)d_in[3];
    const float* We1    = (const float*)d_in[4];
    const float* We2    = (const float*)d_in[5];
    const float* U      = (const float*)d_in[6];
    const float* conv_w = (const float*)d_in[7];
    const float* conv_b = (const float*)d_in[8];
    const float* rel_w  = (const float*)d_in[9];
    float* out = (float*)d_out;

    // workspace (bytes):
    //   px      bf16 128*512*384*2 =  50,331,648
    //   conv_lf bf16 128*512*512*2 =  67,108,864
    //   conv_fl bf16 128*512*512*2 =  67,108,864
    //   cwb     bf16 512*1152*2    =   1,179,648
    //   Qh,Ql   bf16 2*512*512*2   =   1,048,576
    //   v1,v2   f32  2*128*256*4   =     262,144
    //   A1,A2,alpha f32 3*128*512*4=     786,432
    //   total                      = 187,826,176  (< 256 MiB)
    char* p = (char*)d_ws;
    short* px     = (short*)p;  p += (size_t)BB * LL * DD * 2;
    short* convlf = (short*)p;  p += (size_t)BB * LL * NF * 2;
    short* convfl = (short*)p;  p += (size_t)BB * NF * LL * 2;
    short* cwb    = (short*)p;  p += (size_t)NF * DWIN * 2;
    short* QhW    = (short*)p;  p += (size_t)RR * NF * 2;
    short* QlW    = (short*)p;  p += (size_t)RR * NF * 2;
    float* v1     = (float*)p;  p += (size_t)BB * DW * 4;
    float* v2     = (float*)p;  p += (size_t)BB * DW * 4;
    float* A1     = (float*)p;  p += (size_t)BB * LL * 4;
    float* A2     = (float*)p;  p += (size_t)BB * LL * 4;
    float* alpha  = (float*)p;  p += (size_t)BB * LL * 4;

    k_pack_px<<<(BB * LL * DD) / 256, 256, 0, stream>>>(x, posVec, px);
    k_pack_w<<<(NF * DWIN) / 256, 256, 0, stream>>>(conv_w, cwb);
    k_ve<<<BB, DW, 0, stream>>>(We1, We2, e1, e2, v1, v2);
    k_logits<<<BB * LL, DW, 0, stream>>>(x, v1, v2, A1, A2);
    k_alpha<<<BB, LL, 0, stream>>>(A1, A2, alpha);
    k_w2t<<<dim3(NF / 64, RR / 64), 256, 0, stream>>>(U, rel_w, QhW, QlW);
    k_conv_mfma<<<dim3(NF / 128, LL / 128, BB), 256, 0, stream>>>(px, cwb, conv_b, alpha, convlf);
    k_transpose<<<dim3(NF / 64, LL / 64, BB), 256, 0, stream>>>(convlf, convfl);
    hipMemsetAsync(d_out, 0, (size_t)BB * NF * sizeof(float), stream);
    k_flash<<<dim3(RR / 32, BB), 256, 0, stream>>>(QhW, QlW, convlf, convfl, out);
    hipMemcpyAsync(out + BB * NF, rel_w, (size_t)NF * RR * sizeof(float),
                   hipMemcpyDeviceToDevice, stream);
}

// Round 4
// 531.920 us; speedup vs baseline: 6.5699x; 1.5563x over previous
//
#include <hip/hip_runtime.h>
#include <hip/hip_bf16.h>

#define BB 128
#define LL 512
#define DW 256
#define DP 64
#define NF 512
#define DD 384       // D = DW + 2*DP
#define DWIN 1152    // 3*D
#define RR 512       // nr

typedef __attribute__((ext_vector_type(8))) short short8;
typedef __attribute__((ext_vector_type(8))) _Float16 half8;
typedef __attribute__((ext_vector_type(4))) float f32x4;

__device__ inline short f2b(float v) {
    __hip_bfloat16 h = __float2bfloat16(v);
    return *reinterpret_cast<short*>(&h);
}
__device__ inline float b2f(short s) {
    unsigned u = ((unsigned)(unsigned short)s) << 16;
    return __uint_as_float(u);
}

// ---------- small kernels (fp32-exact path for alpha) ----------
__global__ void k_ve(const float* __restrict__ We1, const float* __restrict__ We2,
                     const float* __restrict__ e1, const float* __restrict__ e2,
                     float* __restrict__ v1, float* __restrict__ v2) {
    int b = blockIdx.x;
    int d = threadIdx.x; // 256
    __shared__ float s1[DW], s2[DW];
    s1[d] = e1[b * DW + d];
    s2[d] = e2[b * DW + d];
    __syncthreads();
    float a1 = 0.f, a2 = 0.f;
    for (int e = 0; e < DW; ++e) {
        a1 += We1[d * DW + e] * s1[e];
        a2 += We2[d * DW + e] * s2[e];
    }
    v1[b * DW + d] = a1;
    v2[b * DW + d] = a2;
}

__global__ void k_logits(const float* __restrict__ x,
                         const float* __restrict__ v1, const float* __restrict__ v2,
                         float* __restrict__ A1, float* __restrict__ A2) {
    int bl = blockIdx.x;
    int b = bl / LL;
    int t = threadIdx.x; // 256
    float xv = x[(size_t)bl * DW + t];
    float p1 = xv * v1[b * DW + t];
    float p2 = xv * v2[b * DW + t];
    for (int off = 32; off; off >>= 1) {
        p1 += __shfl_down(p1, off);
        p2 += __shfl_down(p2, off);
    }
    __shared__ float r1[4], r2[4];
    int w = t >> 6;
    if ((t & 63) == 0) { r1[w] = p1; r2[w] = p2; }
    __syncthreads();
    if (t == 0) {
        A1[bl] = r1[0] + r1[1] + r1[2] + r1[3];
        A2[bl] = r2[0] + r2[1] + r2[2] + r2[3];
    }
}

__global__ void k_alpha(const float* __restrict__ A1, const float* __restrict__ A2,
                        float* __restrict__ alpha) {
    int b = blockIdx.x;
    int l = threadIdx.x; // 512
    __shared__ float s[LL];
    float a1 = A1[b * LL + l], a2 = A2[b * LL + l];

    s[l] = a1; __syncthreads();
    for (int st = 256; st; st >>= 1) { if (l < st) s[l] = fmaxf(s[l], s[l + st]); __syncthreads(); }
    float m1 = s[0]; __syncthreads();
    float e1x = expf(a1 - m1);
    s[l] = e1x; __syncthreads();
    for (int st = 256; st; st >>= 1) { if (l < st) s[l] += s[l + st]; __syncthreads(); }
    float d1 = s[0]; __syncthreads();

    s[l] = a2; __syncthreads();
    for (int st = 256; st; st >>= 1) { if (l < st) s[l] = fmaxf(s[l], s[l + st]); __syncthreads(); }
    float m2 = s[0]; __syncthreads();
    float e2x = expf(a2 - m2);
    s[l] = e2x; __syncthreads();
    for (int st = 256; st; st >>= 1) { if (l < st) s[l] += s[l + st]; __syncthreads(); }
    float d2 = s[0];

    alpha[b * LL + l] = 0.5f * (e1x / d1 + e2x / d2);
}

// ---------- packing ----------
__global__ void k_pack_px(const float* __restrict__ x, const float* __restrict__ pv,
                          short* __restrict__ px) {
    int idx = blockIdx.x * 256 + threadIdx.x;   // 128*512*384
    int d = idx % DD;
    int bl = idx / DD;
    float v = (d < DW) ? x[(size_t)bl * DW + d] : pv[(size_t)bl * (2 * DP) + (d - DW)];
    px[idx] = f2b(v);
}

__global__ void k_pack_w(const float* __restrict__ cw, short* __restrict__ cwb) {
    int idx = blockIdx.x * 256 + threadIdx.x;   // 512*1152
    cwb[idx] = f2b(cw[idx]);
}

// ---------- W2t[r][f] = sum_t rel_w[r,t]*U[f,t], split hi/lo bf16 ----------
__global__ void k_w2t(const float* __restrict__ U, const float* __restrict__ relw,
                      short* __restrict__ Qh, short* __restrict__ Ql) {
    __shared__ float As[16][65], Bs[16][65];
    int r0 = blockIdx.y * 64, f0 = blockIdx.x * 64;
    int tid = threadIdx.x, ty = tid >> 4, tx = tid & 15;
    float acc[4][4] = {};
    for (int k0 = 0; k0 < NF; k0 += 16) {
        for (int i = 0; i < 4; ++i) {
            int lin = tid + 256 * i;
            int kk = lin & 15, mm = lin >> 4;
            As[kk][mm] = relw[(r0 + mm) * NF + k0 + kk];
            Bs[kk][mm] = U[(f0 + mm) * NF + k0 + kk];
        }
        __syncthreads();
        for (int kk = 0; kk < 16; ++kk) {
            float av[4], bv[4];
            for (int i = 0; i < 4; ++i) av[i] = As[kk][ty * 4 + i];
            for (int j = 0; j < 4; ++j) bv[j] = Bs[kk][tx * 4 + j];
            for (int i = 0; i < 4; ++i)
                for (int j = 0; j < 4; ++j) acc[i][j] += av[i] * bv[j];
        }
        __syncthreads();
    }
    for (int i = 0; i < 4; ++i)
        for (int j = 0; j < 4; ++j) {
            float vv = acc[i][j];
            short hi = f2b(vv);
            size_t o = (size_t)(r0 + ty * 4 + i) * NF + f0 + tx * 4 + j;
            Qh[o] = hi;
            Ql[o] = f2b(vv - b2f(hi));
        }
}

// ---------- conv MFMA: D[m=l, n=f] = sum_k pxwin[l,k]*conv_w[f,k] ----------
__global__ __launch_bounds__(256) void k_conv_mfma(
    const short* __restrict__ px, const short* __restrict__ cw,
    const float* __restrict__ conv_b, const float* __restrict__ alpha,
    short* __restrict__ conv_lf) {
    int b = blockIdx.z;
    int l0 = blockIdx.y * 128;
    int f0 = blockIdx.x * 128;
    int tid = threadIdx.x;
    int lane = tid & 63, w = tid >> 6;
    int wm = w >> 1, wn = w & 1;
    int lr = lane & 15, lg = lane >> 4;

    __shared__ short As[128][40];
    __shared__ short Bs[128][40];

    f32x4 acc[4][4];
    for (int i = 0; i < 4; ++i)
        for (int j = 0; j < 4; ++j) acc[i][j] = (f32x4){0.f, 0.f, 0.f, 0.f};

    for (int kb = 0; kb < 36; ++kb) {
        int k0 = kb * 32;
        int j = k0 / DD;
        int d0 = k0 - j * DD;
#pragma unroll
        for (int i = 0; i < 2; ++i) {
            int lin = tid + 256 * i;
            int row = lin >> 2;
            int q = lin & 3;
            int gl = l0 + row - 1 + j;
            short8 v = (short8){0, 0, 0, 0, 0, 0, 0, 0};
            if (gl >= 0 && gl < LL)
                v = *(const short8*)(px + ((size_t)b * LL + gl) * DD + d0 + q * 8);
            *(short8*)(&As[row][q * 8]) = v;
            short8 u = *(const short8*)(cw + (size_t)(f0 + row) * DWIN + k0 + q * 8);
            *(short8*)(&Bs[row][q * 8]) = u;
        }
        __syncthreads();
        short8 af[4], bf[4];
#pragma unroll
        for (int mi = 0; mi < 4; ++mi)
            af[mi] = *(const short8*)(&As[wm * 64 + mi * 16 + lr][lg * 8]);
#pragma unroll
        for (int ni = 0; ni < 4; ++ni)
            bf[ni] = *(const short8*)(&Bs[wn * 64 + ni * 16 + lr][lg * 8]);
#pragma unroll
        for (int mi = 0; mi < 4; ++mi)
#pragma unroll
            for (int ni = 0; ni < 4; ++ni)
                acc[mi][ni] = __builtin_amdgcn_mfma_f32_16x16x32_bf16(
                    af[mi], bf[ni], acc[mi][ni], 0, 0, 0);
        __syncthreads();
    }

    int lbase = l0 + wm * 64, fbase = f0 + wn * 64;
#pragma unroll
    for (int mi = 0; mi < 4; ++mi) {
        f32x4 av = *(const f32x4*)(alpha + (size_t)b * LL + lbase + mi * 16 + lg * 4);
#pragma unroll
        for (int ni = 0; ni < 4; ++ni) {
            int f = fbase + ni * 16 + lr;
            float bias = conv_b[f];
#pragma unroll
            for (int r = 0; r < 4; ++r) {
                int l = lbase + mi * 16 + lg * 4 + r;
                float val = tanhf(av[r] * acc[mi][ni][r] + bias);
                conv_lf[((size_t)b * LL + l) * NF + f] = f2b(val);
            }
        }
    }
}

// ---------- transpose conv_lf[b,l,f] -> conv_fl[b,f,l] ----------
__global__ __launch_bounds__(256) void k_transpose(const short* __restrict__ src,
                                                   short* __restrict__ dst) {
    int b = blockIdx.z;
    int l0 = blockIdx.y * 64, f0 = blockIdx.x * 64;
    __shared__ short T[64][72];
    int tid = threadIdx.x;
#pragma unroll
    for (int i = 0; i < 2; ++i) {
        int lin = tid + 256 * i;
        int lrow = lin & 63, q = lin >> 6;
        short8 v = *(const short8*)(src + ((size_t)b * LL + l0 + lrow) * NF + f0 + q * 8);
#pragma unroll
        for (int jj = 0; jj < 8; ++jj) T[q * 8 + jj][lrow] = v[jj];
    }
    __syncthreads();
#pragma unroll
    for (int i = 0; i < 2; ++i) {
        int lin = tid + 256 * i;
        int frow = lin & 63, q = lin >> 6;
        short8 v = *(const short8*)(&T[frow][q * 8]);
        *(short8*)(dst + ((size_t)b * NF + f0 + frow) * LL + l0 + q * 8) = v;
    }
}

// ---------- G MFMA: Gp[b][r][l] = sum_f (Qh+Ql)[r,f]*conv_lf[b,l,f], f16 out ----------
__global__ __launch_bounds__(256) void k_g_mfma(
    const short* __restrict__ Qh, const short* __restrict__ Ql,
    const short* __restrict__ convlf, _Float16* __restrict__ Gp) {
    int b = blockIdx.z;
    int r0 = blockIdx.y * 128;   // M
    int l0 = blockIdx.x * 128;   // N
    int tid = threadIdx.x, lane = tid & 63, w = tid >> 6;
    int wm = w >> 1, wn = w & 1;
    int lr = lane & 15, lg = lane >> 4;

    __shared__ short As[128][40];
    __shared__ short Bs[128][40];

    f32x4 acc[4][4];
    for (int i = 0; i < 4; ++i)
        for (int j = 0; j < 4; ++j) acc[i][j] = (f32x4){0.f, 0.f, 0.f, 0.f};

    const short* convb = convlf + (size_t)b * LL * NF;
    for (int kb = 0; kb < 32; ++kb) {            // virtual K = 1024 (hi then lo)
        const short* Asrc = (kb < 16) ? Qh : Ql;
        int f0 = (kb & 15) * 32;
#pragma unroll
        for (int i = 0; i < 2; ++i) {
            int lin = tid + 256 * i;
            int row = lin >> 2, q = lin & 3;
            *(short8*)(&As[row][q * 8]) = *(const short8*)(Asrc + (size_t)(r0 + row) * NF + f0 + q * 8);
            *(short8*)(&Bs[row][q * 8]) = *(const short8*)(convb + (size_t)(l0 + row) * NF + f0 + q * 8);
        }
        __syncthreads();
        short8 af[4], bf[4];
#pragma unroll
        for (int mi = 0; mi < 4; ++mi)
            af[mi] = *(const short8*)(&As[wm * 64 + mi * 16 + lr][lg * 8]);
#pragma unroll
        for (int ni = 0; ni < 4; ++ni)
            bf[ni] = *(const short8*)(&Bs[wn * 64 + ni * 16 + lr][lg * 8]);
#pragma unroll
        for (int mi = 0; mi < 4; ++mi)
#pragma unroll
            for (int ni = 0; ni < 4; ++ni)
                acc[mi][ni] = __builtin_amdgcn_mfma_f32_16x16x32_bf16(
                    af[mi], bf[ni], acc[mi][ni], 0, 0, 0);
        __syncthreads();
    }

    int rbase = r0 + wm * 64, lbase = l0 + wn * 64;
#pragma unroll
    for (int mi = 0; mi < 4; ++mi)
#pragma unroll
        for (int ni = 0; ni < 4; ++ni)
#pragma unroll
            for (int rr = 0; rr < 4; ++rr) {
                int r = rbase + mi * 16 + lg * 4 + rr;
                int l = lbase + ni * 16 + lr;
                Gp[((size_t)b * RR + r) * LL + l] = (_Float16)acc[mi][ni][rr];
            }
}

// ---------- softmax over l per (b,r) row: f16 logits -> normalized bf16 P, in place ----------
__global__ __launch_bounds__(256) void k_softmax(_Float16* __restrict__ Gp) {
    const float LOG2E = 1.4426950408889634f;
    int row = blockIdx.x * 4 + (threadIdx.x >> 6);   // b*RR + r
    int lane = threadIdx.x & 63;
    _Float16* base = Gp + (size_t)row * LL;
    half8 hv = *(const half8*)(base + lane * 8);
    float v[8];
#pragma unroll
    for (int j = 0; j < 8; ++j) v[j] = (float)hv[j];
    float m = v[0];
#pragma unroll
    for (int j = 1; j < 8; ++j) m = fmaxf(m, v[j]);
    for (int off = 1; off < 64; off <<= 1) m = fmaxf(m, __shfl_xor(m, off));
    float s = 0.f;
    float p[8];
#pragma unroll
    for (int j = 0; j < 8; ++j) { p[j] = exp2f((v[j] - m) * LOG2E); s += p[j]; }
    for (int off = 1; off < 64; off <<= 1) s += __shfl_xor(s, off);
    float inv = 1.f / s;
    short8 o;
#pragma unroll
    for (int j = 0; j < 8; ++j) o[j] = f2b(p[j] * inv);
    *(short8*)((short*)base + lane * 8) = o;
}

// ---------- wo MFMA: out[b,f] = relu(max_r sum_l conv_fl[b,f,l]*P[b,r,l]) ----------
__global__ __launch_bounds__(256) void k_wo_mfma(
    const short* __restrict__ convfl, const short* __restrict__ P,
    float* __restrict__ out) {
    int b = blockIdx.z;
    int f0 = blockIdx.y * 128;   // M
    int r0 = blockIdx.x * 128;   // N
    int tid = threadIdx.x, lane = tid & 63, w = tid >> 6;
    int wm = w >> 1, wn = w & 1;
    int lr = lane & 15, lg = lane >> 4;

    __shared__ short As[128][40];
    __shared__ short Bs[128][40];

    f32x4 acc[4][4];
    for (int i = 0; i < 4; ++i)
        for (int j = 0; j < 4; ++j) acc[i][j] = (f32x4){0.f, 0.f, 0.f, 0.f};

    const short* Ab = convfl + (size_t)b * NF * LL;
    const short* Bb = P + (size_t)b * RR * LL;
    for (int kb = 0; kb < 16; ++kb) {
        int k0 = kb * 32;
#pragma unroll
        for (int i = 0; i < 2; ++i) {
            int lin = tid + 256 * i;
            int row = lin >> 2, q = lin & 3;
            *(short8*)(&As[row][q * 8]) = *(const short8*)(Ab + (size_t)(f0 + row) * LL + k0 + q * 8);
            *(short8*)(&Bs[row][q * 8]) = *(const short8*)(Bb + (size_t)(r0 + row) * LL + k0 + q * 8);
        }
        __syncthreads();
        short8 af[4], bf[4];
#pragma unroll
        for (int mi = 0; mi < 4; ++mi)
            af[mi] = *(const short8*)(&As[wm * 64 + mi * 16 + lr][lg * 8]);
#pragma unroll
        for (int ni = 0; ni < 4; ++ni)
            bf[ni] = *(const short8*)(&Bs[wn * 64 + ni * 16 + lr][lg * 8]);
#pragma unroll
        for (int mi = 0; mi < 4; ++mi)
#pragma unroll
            for (int ni = 0; ni < 4; ++ni)
                acc[mi][ni] = __builtin_amdgcn_mfma_f32_16x16x32_bf16(
                    af[mi], bf[ni], acc[mi][ni], 0, 0, 0);
        __syncthreads();
    }

    int fbase = f0 + wm * 64;
#pragma unroll
    for (int mi = 0; mi < 4; ++mi)
#pragma unroll
        for (int rr = 0; rr < 4; ++rr) {
            float m = acc[mi][0][rr];
#pragma unroll
            for (int ni = 1; ni < 4; ++ni) m = fmaxf(m, acc[mi][ni][rr]);
            m = fmaxf(m, __shfl_xor(m, 1));
            m = fmaxf(m, __shfl_xor(m, 2));
            m = fmaxf(m, __shfl_xor(m, 4));
            m = fmaxf(m, __shfl_xor(m, 8));
            if (lr == 0 && m > 0.f) {
                int f = fbase + mi * 16 + lg * 4 + rr;
                atomicMax((int*)&out[(size_t)b * NF + f], __float_as_int(m));
            }
        }
}

extern "C" void kernel_launch(void* const* d_in, const int* in_sizes, int n_in,
                              void* d_out, int out_size, void* d_ws, size_t ws_size,
                              hipStream_t stream) {
    const float* x      = (const float*)d_in[0];
    const float* e1     = (const float*)d_in[1];
    const float* e2     = (const float*)d_in[2];
    const float* posVec = (const float*)d_in[3];
    const float* We1    = (const float*)d_in[4];
    const float* We2    = (const float*)d_in[5];
    const float* U      = (const float*)d_in[6];
    const float* conv_w = (const float*)d_in[7];
    const float* conv_b = (const float*)d_in[8];
    const float* rel_w  = (const float*)d_in[9];
    float* out = (float*)d_out;

    // workspace (bytes):
    //   convlf  bf16 128*512*512*2 =  67,108,864
    //   convfl  bf16 128*512*512*2 =  67,108,864
    //   GpRegion      f16 67,108,864  (px bf16 50,331,648 aliased at start; dead before Gp written)
    //   cwb 1,179,648 | Qh+Ql 1,048,576 | v1,v2 262,144 | A1,A2,alpha 786,432
    //   total = 204,603,392
    char* p = (char*)d_ws;
    short* convlf = (short*)p;  p += (size_t)BB * LL * NF * 2;
    short* convfl = (short*)p;  p += (size_t)BB * NF * LL * 2;
    char* gpr     = p;          p += (size_t)BB * RR * LL * 2;
    short* px     = (short*)gpr;            // alias: dead after k_conv_mfma
    _Float16* Gp  = (_Float16*)gpr;
    short* cwb    = (short*)p;  p += (size_t)NF * DWIN * 2;
    short* QhW    = (short*)p;  p += (size_t)RR * NF * 2;
    short* QlW    = (short*)p;  p += (size_t)RR * NF * 2;
    float* v1     = (float*)p;  p += (size_t)BB * DW * 4;
    float* v2     = (float*)p;  p += (size_t)BB * DW * 4;
    float* A1     = (float*)p;  p += (size_t)BB * LL * 4;
    float* A2     = (float*)p;  p += (size_t)BB * LL * 4;
    float* alpha  = (float*)p;  p += (size_t)BB * LL * 4;

    k_pack_px<<<(BB * LL * DD) / 256, 256, 0, stream>>>(x, posVec, px);
    k_pack_w<<<(NF * DWIN) / 256, 256, 0, stream>>>(conv_w, cwb);
    k_ve<<<BB, DW, 0, stream>>>(We1, We2, e1, e2, v1, v2);
    k_logits<<<BB * LL, DW, 0, stream>>>(x, v1, v2, A1, A2);
    k_alpha<<<BB, LL, 0, stream>>>(A1, A2, alpha);
    k_w2t<<<dim3(NF / 64, RR / 64), 256, 0, stream>>>(U, rel_w, QhW, QlW);
    k_conv_mfma<<<dim3(NF / 128, LL / 128, BB), 256, 0, stream>>>(px, cwb, conv_b, alpha, convlf);
    k_transpose<<<dim3(NF / 64, LL / 64, BB), 256, 0, stream>>>(convlf, convfl);
    k_g_mfma<<<dim3(LL / 128, RR / 128, BB), 256, 0, stream>>>(QhW, QlW, convlf, Gp);
    k_softmax<<<(BB * RR) / 4, 256, 0, stream>>>(Gp);
    hipMemsetAsync(d_out, 0, (size_t)BB * NF * sizeof(float), stream);
    k_wo_mfma<<<dim3(RR / 128, NF / 128, BB), 256, 0, stream>>>(convfl, (const short*)Gp, out);
    hipMemcpyAsync(out + BB * NF, rel_w, (size_t)NF * RR * sizeof(float),
                   hipMemcpyDeviceToDevice, stream);
}

// Round 5
// 498.226 us; speedup vs baseline: 7.0142x; 1.0676x over previous
//
#include <hip/hip_runtime.h>
#include <hip/hip_bf16.h>

#define BB 128
#define LL 512
#define DW 256
#define DP 64
#define NF 512
#define DD 384       // D = DW + 2*DP
#define DWIN 1152    // 3*D
#define RR 512       // nr

typedef __attribute__((ext_vector_type(8))) short short8;
typedef __attribute__((ext_vector_type(4))) short short4v;
typedef __attribute__((ext_vector_type(8))) _Float16 half8;
typedef __attribute__((ext_vector_type(4))) float f32x4;

__device__ inline short f2b(float v) {
    __hip_bfloat16 h = __float2bfloat16(v);
    return *reinterpret_cast<short*>(&h);
}
__device__ inline float b2f(short s) {
    unsigned u = ((unsigned)(unsigned short)s) << 16;
    return __uint_as_float(u);
}
// XCD-chunked bijective swizzle (nwg % 8 == 0): XCD k gets linear ids [k*chunk,(k+1)*chunk)
__device__ inline int xcd_swz(int bid, int nwg) {
    return (bid & 7) * (nwg >> 3) + (bid >> 3);
}

// ---------- small kernels (fp32-exact path for alpha) ----------
__global__ void k_ve(const float* __restrict__ We1, const float* __restrict__ We2,
                     const float* __restrict__ e1, const float* __restrict__ e2,
                     float* __restrict__ v1, float* __restrict__ v2) {
    int b = blockIdx.x;
    int d = threadIdx.x; // 256
    __shared__ float s1[DW], s2[DW];
    s1[d] = e1[b * DW + d];
    s2[d] = e2[b * DW + d];
    __syncthreads();
    float a1 = 0.f, a2 = 0.f;
    for (int e = 0; e < DW; ++e) {
        a1 += We1[d * DW + e] * s1[e];
        a2 += We2[d * DW + e] * s2[e];
    }
    v1[b * DW + d] = a1;
    v2[b * DW + d] = a2;
}

// one wave per (b,l) row, float4 loads
__global__ __launch_bounds__(256) void k_logits(
    const float* __restrict__ x,
    const float* __restrict__ v1, const float* __restrict__ v2,
    float* __restrict__ A1, float* __restrict__ A2) {
    int row = blockIdx.x * 4 + (threadIdx.x >> 6);   // b*LL + l
    int lane = threadIdx.x & 63;
    int b = row >> 9;
    f32x4 xv = *(const f32x4*)(x + (size_t)row * DW + lane * 4);
    f32x4 w1 = *(const f32x4*)(v1 + b * DW + lane * 4);
    f32x4 w2 = *(const f32x4*)(v2 + b * DW + lane * 4);
    float p1 = xv[0] * w1[0] + xv[1] * w1[1] + xv[2] * w1[2] + xv[3] * w1[3];
    float p2 = xv[0] * w2[0] + xv[1] * w2[1] + xv[2] * w2[2] + xv[3] * w2[3];
    for (int off = 32; off; off >>= 1) {
        p1 += __shfl_down(p1, off);
        p2 += __shfl_down(p2, off);
    }
    if (lane == 0) { A1[row] = p1; A2[row] = p2; }
}

__global__ void k_alpha(const float* __restrict__ A1, const float* __restrict__ A2,
                        float* __restrict__ alpha) {
    int b = blockIdx.x;
    int l = threadIdx.x; // 512
    __shared__ float s[LL];
    float a1 = A1[b * LL + l], a2 = A2[b * LL + l];

    s[l] = a1; __syncthreads();
    for (int st = 256; st; st >>= 1) { if (l < st) s[l] = fmaxf(s[l], s[l + st]); __syncthreads(); }
    float m1 = s[0]; __syncthreads();
    float e1x = expf(a1 - m1);
    s[l] = e1x; __syncthreads();
    for (int st = 256; st; st >>= 1) { if (l < st) s[l] += s[l + st]; __syncthreads(); }
    float d1 = s[0]; __syncthreads();

    s[l] = a2; __syncthreads();
    for (int st = 256; st; st >>= 1) { if (l < st) s[l] = fmaxf(s[l], s[l + st]); __syncthreads(); }
    float m2 = s[0]; __syncthreads();
    float e2x = expf(a2 - m2);
    s[l] = e2x; __syncthreads();
    for (int st = 256; st; st >>= 1) { if (l < st) s[l] += s[l + st]; __syncthreads(); }
    float d2 = s[0];

    alpha[b * LL + l] = 0.5f * (e1x / d1 + e2x / d2);
}

// ---------- W2t[r][f] = sum_t rel_w[r,t]*U[f,t], split hi/lo bf16 ----------
__global__ void k_w2t(const float* __restrict__ U, const float* __restrict__ relw,
                      short* __restrict__ Qh, short* __restrict__ Ql) {
    __shared__ float As[16][65], Bs[16][65];
    int r0 = blockIdx.y * 64, f0 = blockIdx.x * 64;
    int tid = threadIdx.x, ty = tid >> 4, tx = tid & 15;
    float acc[4][4] = {};
    for (int k0 = 0; k0 < NF; k0 += 16) {
        for (int i = 0; i < 4; ++i) {
            int lin = tid + 256 * i;
            int kk = lin & 15, mm = lin >> 4;
            As[kk][mm] = relw[(r0 + mm) * NF + k0 + kk];
            Bs[kk][mm] = U[(f0 + mm) * NF + k0 + kk];
        }
        __syncthreads();
        for (int kk = 0; kk < 16; ++kk) {
            float av[4], bv[4];
            for (int i = 0; i < 4; ++i) av[i] = As[kk][ty * 4 + i];
            for (int j = 0; j < 4; ++j) bv[j] = Bs[kk][tx * 4 + j];
            for (int i = 0; i < 4; ++i)
                for (int j = 0; j < 4; ++j) acc[i][j] += av[i] * bv[j];
        }
        __syncthreads();
    }
    for (int i = 0; i < 4; ++i)
        for (int j = 0; j < 4; ++j) {
            float vv = acc[i][j];
            short hi = f2b(vv);
            size_t o = (size_t)(r0 + ty * 4 + i) * NF + f0 + tx * 4 + j;
            Qh[o] = hi;
            Ql[o] = f2b(vv - b2f(hi));
        }
}

// ---------- conv MFMA: D[m=l, n=f] = sum_k pxwin[l,k]*conv_w[f,k] ----------
// fp32 inputs converted to bf16 during staging; epilogue writes conv_lf AND conv_fl
__global__ __launch_bounds__(256) void k_conv_mfma(
    const float* __restrict__ x, const float* __restrict__ posVec,
    const float* __restrict__ cw,
    const float* __restrict__ conv_b, const float* __restrict__ alpha,
    short* __restrict__ conv_lf, short* __restrict__ conv_fl) {
    int wg = xcd_swz(blockIdx.x, 2048);
    int b = wg >> 4;
    int l0 = ((wg >> 2) & 3) * 128;
    int f0 = (wg & 3) * 128;
    int tid = threadIdx.x;
    int lane = tid & 63, w = tid >> 6;
    int wm = w >> 1, wn = w & 1;
    int lr = lane & 15, lg = lane >> 4;

    __shared__ short As[128][40];
    __shared__ short Bs[128][40];

    f32x4 acc[4][4];
    for (int i = 0; i < 4; ++i)
        for (int j = 0; j < 4; ++j) acc[i][j] = (f32x4){0.f, 0.f, 0.f, 0.f};

    for (int kb = 0; kb < 36; ++kb) {
        int k0 = kb * 32;
        int j = k0 / DD;          // 0..2 (32 | 384: no segment crossing)
        int d0 = k0 - j * DD;
#pragma unroll
        for (int i = 0; i < 2; ++i) {
            int lin = tid + 256 * i;       // 0..511
            int row = lin >> 2;            // 0..127
            int q = lin & 3;
            // ---- A: windowed px row, fp32 -> bf16 ----
            int gl = l0 + row - 1 + j;
            short8 v = (short8){0, 0, 0, 0, 0, 0, 0, 0};
            if (gl >= 0 && gl < LL) {
                int d = d0 + q * 8;        // 8-elem segment never crosses the x/posVec split
                const float* src = (d < DW)
                    ? (x + ((size_t)b * LL + gl) * DW + d)
                    : (posVec + ((size_t)b * LL + gl) * (2 * DP) + (d - DW));
                f32x4 u0 = *(const f32x4*)(src);
                f32x4 u1 = *(const f32x4*)(src + 4);
#pragma unroll
                for (int jj = 0; jj < 4; ++jj) { v[jj] = f2b(u0[jj]); v[jj + 4] = f2b(u1[jj]); }
            }
            *(short8*)(&As[row][q * 8]) = v;
            // ---- B: conv_w row, fp32 -> bf16 ----
            const float* bsrc = cw + (size_t)(f0 + row) * DWIN + k0 + q * 8;
            f32x4 w0 = *(const f32x4*)(bsrc);
            f32x4 w1 = *(const f32x4*)(bsrc + 4);
            short8 u;
#pragma unroll
            for (int jj = 0; jj < 4; ++jj) { u[jj] = f2b(w0[jj]); u[jj + 4] = f2b(w1[jj]); }
            *(short8*)(&Bs[row][q * 8]) = u;
        }
        __syncthreads();
        short8 af[4], bf[4];
#pragma unroll
        for (int mi = 0; mi < 4; ++mi)
            af[mi] = *(const short8*)(&As[wm * 64 + mi * 16 + lr][lg * 8]);
#pragma unroll
        for (int ni = 0; ni < 4; ++ni)
            bf[ni] = *(const short8*)(&Bs[wn * 64 + ni * 16 + lr][lg * 8]);
#pragma unroll
        for (int mi = 0; mi < 4; ++mi)
#pragma unroll
            for (int ni = 0; ni < 4; ++ni)
                acc[mi][ni] = __builtin_amdgcn_mfma_f32_16x16x32_bf16(
                    af[mi], bf[ni], acc[mi][ni], 0, 0, 0);
        __syncthreads();
    }

    int lbase = l0 + wm * 64, fbase = f0 + wn * 64;
#pragma unroll
    for (int mi = 0; mi < 4; ++mi) {
        f32x4 av = *(const f32x4*)(alpha + (size_t)b * LL + lbase + mi * 16 + lg * 4);
        int lrow = lbase + mi * 16 + lg * 4;
#pragma unroll
        for (int ni = 0; ni < 4; ++ni) {
            int f = fbase + ni * 16 + lr;
            float bias = conv_b[f];
            short4v o;
#pragma unroll
            for (int r = 0; r < 4; ++r) {
                float val = tanhf(av[r] * acc[mi][ni][r] + bias);
                short sv = f2b(val);
                o[r] = sv;
                conv_lf[((size_t)b * LL + lrow + r) * NF + f] = sv;
            }
            *(short4v*)(conv_fl + ((size_t)b * NF + f) * LL + lrow) = o;
        }
    }
}

// ---------- G MFMA: Gp[b][r][l] = sum_f (Qh+Ql)[r,f]*conv_lf[b,l,f], f16 out ----------
__global__ __launch_bounds__(256) void k_g_mfma(
    const short* __restrict__ Qh, const short* __restrict__ Ql,
    const short* __restrict__ convlf, _Float16* __restrict__ Gp) {
    int wg = xcd_swz(blockIdx.x, 2048);
    int b = wg >> 4;
    int r0 = ((wg >> 2) & 3) * 128;   // M
    int l0 = (wg & 3) * 128;          // N
    int tid = threadIdx.x, lane = tid & 63, w = tid >> 6;
    int wm = w >> 1, wn = w & 1;
    int lr = lane & 15, lg = lane >> 4;

    __shared__ short As[128][40];
    __shared__ short Bs[128][40];

    f32x4 acc[4][4];
    for (int i = 0; i < 4; ++i)
        for (int j = 0; j < 4; ++j) acc[i][j] = (f32x4){0.f, 0.f, 0.f, 0.f};

    const short* convb = convlf + (size_t)b * LL * NF;
    for (int kb = 0; kb < 32; ++kb) {            // virtual K = 1024 (hi then lo)
        const short* Asrc = (kb < 16) ? Qh : Ql;
        int f0 = (kb & 15) * 32;
#pragma unroll
        for (int i = 0; i < 2; ++i) {
            int lin = tid + 256 * i;
            int row = lin >> 2, q = lin & 3;
            *(short8*)(&As[row][q * 8]) = *(const short8*)(Asrc + (size_t)(r0 + row) * NF + f0 + q * 8);
            *(short8*)(&Bs[row][q * 8]) = *(const short8*)(convb + (size_t)(l0 + row) * NF + f0 + q * 8);
        }
        __syncthreads();
        short8 af[4], bf[4];
#pragma unroll
        for (int mi = 0; mi < 4; ++mi)
            af[mi] = *(const short8*)(&As[wm * 64 + mi * 16 + lr][lg * 8]);
#pragma unroll
        for (int ni = 0; ni < 4; ++ni)
            bf[ni] = *(const short8*)(&Bs[wn * 64 + ni * 16 + lr][lg * 8]);
#pragma unroll
        for (int mi = 0; mi < 4; ++mi)
#pragma unroll
            for (int ni = 0; ni < 4; ++ni)
                acc[mi][ni] = __builtin_amdgcn_mfma_f32_16x16x32_bf16(
                    af[mi], bf[ni], acc[mi][ni], 0, 0, 0);
        __syncthreads();
    }

    int rbase = r0 + wm * 64, lbase = l0 + wn * 64;
#pragma unroll
    for (int mi = 0; mi < 4; ++mi)
#pragma unroll
        for (int ni = 0; ni < 4; ++ni)
#pragma unroll
            for (int rr = 0; rr < 4; ++rr) {
                int r = rbase + mi * 16 + lg * 4 + rr;
                int l = lbase + ni * 16 + lr;
                Gp[((size_t)b * RR + r) * LL + l] = (_Float16)acc[mi][ni][rr];
            }
}

// ---------- softmax over l per (b,r) row: f16 logits -> normalized bf16 P, in place ----------
__global__ __launch_bounds__(256) void k_softmax(_Float16* __restrict__ Gp) {
    const float LOG2E = 1.4426950408889634f;
    int row = blockIdx.x * 4 + (threadIdx.x >> 6);   // b*RR + r
    int lane = threadIdx.x & 63;
    _Float16* base = Gp + (size_t)row * LL;
    half8 hv = *(const half8*)(base + lane * 8);
    float v[8];
#pragma unroll
    for (int j = 0; j < 8; ++j) v[j] = (float)hv[j];
    float m = v[0];
#pragma unroll
    for (int j = 1; j < 8; ++j) m = fmaxf(m, v[j]);
    for (int off = 1; off < 64; off <<= 1) m = fmaxf(m, __shfl_xor(m, off));
    float s = 0.f;
    float p[8];
#pragma unroll
    for (int j = 0; j < 8; ++j) { p[j] = exp2f((v[j] - m) * LOG2E); s += p[j]; }
    for (int off = 1; off < 64; off <<= 1) s += __shfl_xor(s, off);
    float inv = 1.f / s;
    short8 o;
#pragma unroll
    for (int j = 0; j < 8; ++j) o[j] = f2b(p[j] * inv);
    *(short8*)((short*)base + lane * 8) = o;
}

// ---------- wo MFMA: out[b,f] = relu(max_r sum_l conv_fl[b,f,l]*P[b,r,l]) ----------
__global__ __launch_bounds__(256) void k_wo_mfma(
    const short* __restrict__ convfl, const short* __restrict__ P,
    float* __restrict__ out) {
    int wg = xcd_swz(blockIdx.x, 2048);
    int b = wg >> 4;
    int f0 = ((wg >> 2) & 3) * 128;   // M
    int r0 = (wg & 3) * 128;          // N
    int tid = threadIdx.x, lane = tid & 63, w = tid >> 6;
    int wm = w >> 1, wn = w & 1;
    int lr = lane & 15, lg = lane >> 4;

    __shared__ short As[128][40];
    __shared__ short Bs[128][40];

    f32x4 acc[4][4];
    for (int i = 0; i < 4; ++i)
        for (int j = 0; j < 4; ++j) acc[i][j] = (f32x4){0.f, 0.f, 0.f, 0.f};

    const short* Ab = convfl + (size_t)b * NF * LL;
    const short* Bb = P + (size_t)b * RR * LL;
    for (int kb = 0; kb < 16; ++kb) {
        int k0 = kb * 32;
#pragma unroll
        for (int i = 0; i < 2; ++i) {
            int lin = tid + 256 * i;
            int row = lin >> 2, q = lin & 3;
            *(short8*)(&As[row][q * 8]) = *(const short8*)(Ab + (size_t)(f0 + row) * LL + k0 + q * 8);
            *(short8*)(&Bs[row][q * 8]) = *(const short8*)(Bb + (size_t)(r0 + row) * LL + k0 + q * 8);
        }
        __syncthreads();
        short8 af[4], bf[4];
#pragma unroll
        for (int mi = 0; mi < 4; ++mi)
            af[mi] = *(const short8*)(&As[wm * 64 + mi * 16 + lr][lg * 8]);
#pragma unroll
        for (int ni = 0; ni < 4; ++ni)
            bf[ni] = *(const short8*)(&Bs[wn * 64 + ni * 16 + lr][lg * 8]);
#pragma unroll
        for (int mi = 0; mi < 4; ++mi)
#pragma unroll
            for (int ni = 0; ni < 4; ++ni)
                acc[mi][ni] = __builtin_amdgcn_mfma_f32_16x16x32_bf16(
                    af[mi], bf[ni], acc[mi][ni], 0, 0, 0);
        __syncthreads();
    }

    int fbase = f0 + wm * 64;
#pragma unroll
    for (int mi = 0; mi < 4; ++mi)
#pragma unroll
        for (int rr = 0; rr < 4; ++rr) {
            float m = acc[mi][0][rr];
#pragma unroll
            for (int ni = 1; ni < 4; ++ni) m = fmaxf(m, acc[mi][ni][rr]);
            m = fmaxf(m, __shfl_xor(m, 1));
            m = fmaxf(m, __shfl_xor(m, 2));
            m = fmaxf(m, __shfl_xor(m, 4));
            m = fmaxf(m, __shfl_xor(m, 8));
            if (lr == 0 && m > 0.f) {
                int f = fbase + mi * 16 + lg * 4 + rr;
                atomicMax((int*)&out[(size_t)b * NF + f], __float_as_int(m));
            }
        }
}

extern "C" void kernel_launch(void* const* d_in, const int* in_sizes, int n_in,
                              void* d_out, int out_size, void* d_ws, size_t ws_size,
                              hipStream_t stream) {
    const float* x      = (const float*)d_in[0];
    const float* e1     = (const float*)d_in[1];
    const float* e2     = (const float*)d_in[2];
    const float* posVec = (const float*)d_in[3];
    const float* We1    = (const float*)d_in[4];
    const float* We2    = (const float*)d_in[5];
    const float* U      = (const float*)d_in[6];
    const float* conv_w = (const float*)d_in[7];
    const float* conv_b = (const float*)d_in[8];
    const float* rel_w  = (const float*)d_in[9];
    float* out = (float*)d_out;

    // workspace (bytes):
    //   convlf  bf16 128*512*512*2 =  67,108,864
    //   convfl  bf16 128*512*512*2 =  67,108,864
    //   Gp      f16  128*512*512*2 =  67,108,864
    //   Qh+Ql 1,048,576 | v1,v2 262,144 | A1,A2,alpha 786,432
    //   total = 203,423,744  (< 256 MiB)
    char* p = (char*)d_ws;
    short* convlf = (short*)p;  p += (size_t)BB * LL * NF * 2;
    short* convfl = (short*)p;  p += (size_t)BB * NF * LL * 2;
    _Float16* Gp  = (_Float16*)p;  p += (size_t)BB * RR * LL * 2;
    short* QhW    = (short*)p;  p += (size_t)RR * NF * 2;
    short* QlW    = (short*)p;  p += (size_t)RR * NF * 2;
    float* v1     = (float*)p;  p += (size_t)BB * DW * 4;
    float* v2     = (float*)p;  p += (size_t)BB * DW * 4;
    float* A1     = (float*)p;  p += (size_t)BB * LL * 4;
    float* A2     = (float*)p;  p += (size_t)BB * LL * 4;
    float* alpha  = (float*)p;  p += (size_t)BB * LL * 4;

    k_ve<<<BB, DW, 0, stream>>>(We1, We2, e1, e2, v1, v2);
    k_logits<<<(BB * LL) / 4, 256, 0, stream>>>(x, v1, v2, A1, A2);
    k_alpha<<<BB, LL, 0, stream>>>(A1, A2, alpha);
    k_w2t<<<dim3(NF / 64, RR / 64), 256, 0, stream>>>(U, rel_w, QhW, QlW);
    k_conv_mfma<<<2048, 256, 0, stream>>>(x, posVec, conv_w, conv_b, alpha, convlf, convfl);
    k_g_mfma<<<2048, 256, 0, stream>>>(QhW, QlW, convlf, Gp);
    k_softmax<<<(BB * RR) / 4, 256, 0, stream>>>(Gp);
    hipMemsetAsync(d_out, 0, (size_t)BB * NF * sizeof(float), stream);
    k_wo_mfma<<<2048, 256, 0, stream>>>(convfl, (const short*)Gp, out);
    hipMemcpyAsync(out + BB * NF, rel_w, (size_t)NF * RR * sizeof(float),
                   hipMemcpyDeviceToDevice, stream);
}

// Round 6
// 490.434 us; speedup vs baseline: 7.1256x; 1.0159x over previous
//
#include <hip/hip_runtime.h>
#include <hip/hip_bf16.h>

#define BB 128
#define LL 512
#define DW 256
#define DP 64
#define NF 512
#define DD 384       // D = DW + 2*DP
#define DWIN 1152    // 3*D
#define RR 512       // nr

typedef __attribute__((ext_vector_type(8))) short short8;
typedef __attribute__((ext_vector_type(4))) short short4v;
typedef __attribute__((ext_vector_type(8))) _Float16 half8;
typedef __attribute__((ext_vector_type(4))) float f32x4;

__device__ inline short f2b(float v) {
    __hip_bfloat16 h = __float2bfloat16(v);
    return *reinterpret_cast<short*>(&h);
}
__device__ inline float b2f(short s) {
    unsigned u = ((unsigned)(unsigned short)s) << 16;
    return __uint_as_float(u);
}
// XCD-chunked bijective swizzle (nwg % 8 == 0)
__device__ inline int xcd_swz(int bid, int nwg) {
    return (bid & 7) * (nwg >> 3) + (bid >> 3);
}

// ---------- small kernels (fp32-exact path for alpha) ----------
__global__ void k_ve(const float* __restrict__ We1, const float* __restrict__ We2,
                     const float* __restrict__ e1, const float* __restrict__ e2,
                     float* __restrict__ v1, float* __restrict__ v2) {
    int b = blockIdx.x;
    int d = threadIdx.x; // 256
    __shared__ float s1[DW], s2[DW];
    s1[d] = e1[b * DW + d];
    s2[d] = e2[b * DW + d];
    __syncthreads();
    float a1 = 0.f, a2 = 0.f;
    for (int e = 0; e < DW; ++e) {
        a1 += We1[d * DW + e] * s1[e];
        a2 += We2[d * DW + e] * s2[e];
    }
    v1[b * DW + d] = a1;
    v2[b * DW + d] = a2;
}

// one wave per (b,l) row, float4 loads
__global__ __launch_bounds__(256) void k_logits(
    const float* __restrict__ x,
    const float* __restrict__ v1, const float* __restrict__ v2,
    float* __restrict__ A1, float* __restrict__ A2) {
    int row = blockIdx.x * 4 + (threadIdx.x >> 6);   // b*LL + l
    int lane = threadIdx.x & 63;
    int b = row >> 9;
    f32x4 xv = *(const f32x4*)(x + (size_t)row * DW + lane * 4);
    f32x4 w1 = *(const f32x4*)(v1 + b * DW + lane * 4);
    f32x4 w2 = *(const f32x4*)(v2 + b * DW + lane * 4);
    float p1 = xv[0] * w1[0] + xv[1] * w1[1] + xv[2] * w1[2] + xv[3] * w1[3];
    float p2 = xv[0] * w2[0] + xv[1] * w2[1] + xv[2] * w2[2] + xv[3] * w2[3];
    for (int off = 32; off; off >>= 1) {
        p1 += __shfl_down(p1, off);
        p2 += __shfl_down(p2, off);
    }
    if (lane == 0) { A1[row] = p1; A2[row] = p2; }
}

__global__ void k_alpha(const float* __restrict__ A1, const float* __restrict__ A2,
                        float* __restrict__ alpha) {
    int b = blockIdx.x;
    int l = threadIdx.x; // 512
    __shared__ float s[LL];
    float a1 = A1[b * LL + l], a2 = A2[b * LL + l];

    s[l] = a1; __syncthreads();
    for (int st = 256; st; st >>= 1) { if (l < st) s[l] = fmaxf(s[l], s[l + st]); __syncthreads(); }
    float m1 = s[0]; __syncthreads();
    float e1x = expf(a1 - m1);
    s[l] = e1x; __syncthreads();
    for (int st = 256; st; st >>= 1) { if (l < st) s[l] += s[l + st]; __syncthreads(); }
    float d1 = s[0]; __syncthreads();

    s[l] = a2; __syncthreads();
    for (int st = 256; st; st >>= 1) { if (l < st) s[l] = fmaxf(s[l], s[l + st]); __syncthreads(); }
    float m2 = s[0]; __syncthreads();
    float e2x = expf(a2 - m2);
    s[l] = e2x; __syncthreads();
    for (int st = 256; st; st >>= 1) { if (l < st) s[l] += s[l + st]; __syncthreads(); }
    float d2 = s[0];

    alpha[b * LL + l] = 0.5f * (e1x / d1 + e2x / d2);
}

// ---------- W2t[r][f] = sum_t rel_w[r,t]*U[f,t], split hi/lo bf16 ----------
__global__ void k_w2t(const float* __restrict__ U, const float* __restrict__ relw,
                      short* __restrict__ Qh, short* __restrict__ Ql) {
    __shared__ float As[16][65], Bs[16][65];
    int r0 = blockIdx.y * 64, f0 = blockIdx.x * 64;
    int tid = threadIdx.x, ty = tid >> 4, tx = tid & 15;
    float acc[4][4] = {};
    for (int k0 = 0; k0 < NF; k0 += 16) {
        for (int i = 0; i < 4; ++i) {
            int lin = tid + 256 * i;
            int kk = lin & 15, mm = lin >> 4;
            As[kk][mm] = relw[(r0 + mm) * NF + k0 + kk];
            Bs[kk][mm] = U[(f0 + mm) * NF + k0 + kk];
        }
        __syncthreads();
        for (int kk = 0; kk < 16; ++kk) {
            float av[4], bv[4];
            for (int i = 0; i < 4; ++i) av[i] = As[kk][ty * 4 + i];
            for (int j = 0; j < 4; ++j) bv[j] = Bs[kk][tx * 4 + j];
            for (int i = 0; i < 4; ++i)
                for (int j = 0; j < 4; ++j) acc[i][j] += av[i] * bv[j];
        }
        __syncthreads();
    }
    for (int i = 0; i < 4; ++i)
        for (int j = 0; j < 4; ++j) {
            float vv = acc[i][j];
            short hi = f2b(vv);
            size_t o = (size_t)(r0 + ty * 4 + i) * NF + f0 + tx * 4 + j;
            Qh[o] = hi;
            Ql[o] = f2b(vv - b2f(hi));
        }
}

// ---------- conv MFMA: D[m=l, n=f] = sum_k pxwin[l,k]*conv_w[f,k] ----------
// fp32 inputs converted to bf16 during staging; epilogue writes conv_lf (direct)
// and conv_fl (via LDS transpose, fully coalesced 16B stores).
__global__ __launch_bounds__(256) void k_conv_mfma(
    const float* __restrict__ x, const float* __restrict__ posVec,
    const float* __restrict__ cw,
    const float* __restrict__ conv_b, const float* __restrict__ alpha,
    short* __restrict__ conv_lf, short* __restrict__ conv_fl) {
    int wg = xcd_swz(blockIdx.x, 2048);
    int b = wg >> 4;
    int l0 = ((wg >> 2) & 3) * 128;
    int f0 = (wg & 3) * 128;
    int tid = threadIdx.x;
    int lane = tid & 63, w = tid >> 6;
    int wm = w >> 1, wn = w & 1;
    int lr = lane & 15, lg = lane >> 4;

    // union: K-loop uses As/Bs (2*10240B); epilogue reuses as T[128][136] (34816B)
    __shared__ __align__(16) char smem[34816];
    short (*As)[40] = (short(*)[40])smem;
    short (*Bs)[40] = (short(*)[40])(smem + 10240);
    short (*T)[136] = (short(*)[136])smem;

    f32x4 acc[4][4];
    for (int i = 0; i < 4; ++i)
        for (int j = 0; j < 4; ++j) acc[i][j] = (f32x4){0.f, 0.f, 0.f, 0.f};

    for (int kb = 0; kb < 36; ++kb) {
        int k0 = kb * 32;
        int j = k0 / DD;          // 0..2 (32 | 384: no segment crossing)
        int d0 = k0 - j * DD;
#pragma unroll
        for (int i = 0; i < 2; ++i) {
            int lin = tid + 256 * i;       // 0..511
            int row = lin >> 2;            // 0..127
            int q = lin & 3;
            // ---- A: windowed px row, fp32 -> bf16 ----
            int gl = l0 + row - 1 + j;
            short8 v = (short8){0, 0, 0, 0, 0, 0, 0, 0};
            if (gl >= 0 && gl < LL) {
                int d = d0 + q * 8;        // 8-elem segment never crosses x/posVec split
                const float* src = (d < DW)
                    ? (x + ((size_t)b * LL + gl) * DW + d)
                    : (posVec + ((size_t)b * LL + gl) * (2 * DP) + (d - DW));
                f32x4 u0 = *(const f32x4*)(src);
                f32x4 u1 = *(const f32x4*)(src + 4);
#pragma unroll
                for (int jj = 0; jj < 4; ++jj) { v[jj] = f2b(u0[jj]); v[jj + 4] = f2b(u1[jj]); }
            }
            *(short8*)(&As[row][q * 8]) = v;
            // ---- B: conv_w row, fp32 -> bf16 ----
            const float* bsrc = cw + (size_t)(f0 + row) * DWIN + k0 + q * 8;
            f32x4 w0 = *(const f32x4*)(bsrc);
            f32x4 w1 = *(const f32x4*)(bsrc + 4);
            short8 u;
#pragma unroll
            for (int jj = 0; jj < 4; ++jj) { u[jj] = f2b(w0[jj]); u[jj + 4] = f2b(w1[jj]); }
            *(short8*)(&Bs[row][q * 8]) = u;
        }
        __syncthreads();
        short8 af[4], bf[4];
#pragma unroll
        for (int mi = 0; mi < 4; ++mi)
            af[mi] = *(const short8*)(&As[wm * 64 + mi * 16 + lr][lg * 8]);
#pragma unroll
        for (int ni = 0; ni < 4; ++ni)
            bf[ni] = *(const short8*)(&Bs[wn * 64 + ni * 16 + lr][lg * 8]);
#pragma unroll
        for (int mi = 0; mi < 4; ++mi)
#pragma unroll
            for (int ni = 0; ni < 4; ++ni)
                acc[mi][ni] = __builtin_amdgcn_mfma_f32_16x16x32_bf16(
                    af[mi], bf[ni], acc[mi][ni], 0, 0, 0);
        __syncthreads();
    }
    // after the loop's closing barrier all LDS reads are done -> safe to reuse smem as T

    int lbase = l0 + wm * 64, fbase = f0 + wn * 64;
#pragma unroll
    for (int mi = 0; mi < 4; ++mi) {
        f32x4 av = *(const f32x4*)(alpha + (size_t)b * LL + lbase + mi * 16 + lg * 4);
        int lrow = lbase + mi * 16 + lg * 4;
#pragma unroll
        for (int ni = 0; ni < 4; ++ni) {
            int f = fbase + ni * 16 + lr;
            float bias = conv_b[f];
            short4v o;
#pragma unroll
            for (int r = 0; r < 4; ++r) {
                float val = tanhf(av[r] * acc[mi][ni][r] + bias);
                short sv = f2b(val);
                o[r] = sv;
                conv_lf[((size_t)b * LL + lrow + r) * NF + f] = sv;
            }
            // stage [f_local][l_local] for coalesced conv_fl write
            *(short4v*)(&T[wn * 64 + ni * 16 + lr][wm * 64 + mi * 16 + lg * 4]) = o;
        }
    }
    __syncthreads();
#pragma unroll
    for (int i = 0; i < 8; ++i) {
        int lin = tid + 256 * i;          // 0..2047
        int frow = lin >> 4;              // 0..127
        int q = lin & 15;                 // 0..15
        short8 v = *(const short8*)(&T[frow][q * 8]);
        *(short8*)(conv_fl + ((size_t)b * NF + f0 + frow) * LL + l0 + q * 8) = v;
    }
}

// ---------- G MFMA: Gp[b][r][l] = sum_f (Qh+Ql)[r,f]*conv_lf[b,l,f], f16 out ----------
__global__ __launch_bounds__(256) void k_g_mfma(
    const short* __restrict__ Qh, const short* __restrict__ Ql,
    const short* __restrict__ convlf, _Float16* __restrict__ Gp) {
    int wg = xcd_swz(blockIdx.x, 2048);
    int b = wg >> 4;
    int r0 = ((wg >> 2) & 3) * 128;   // M
    int l0 = (wg & 3) * 128;          // N
    int tid = threadIdx.x, lane = tid & 63, w = tid >> 6;
    int wm = w >> 1, wn = w & 1;
    int lr = lane & 15, lg = lane >> 4;

    __shared__ short As[128][40];
    __shared__ short Bs[128][40];

    f32x4 acc[4][4];
    for (int i = 0; i < 4; ++i)
        for (int j = 0; j < 4; ++j) acc[i][j] = (f32x4){0.f, 0.f, 0.f, 0.f};

    const short* convb = convlf + (size_t)b * LL * NF;
    for (int kb = 0; kb < 32; ++kb) {            // virtual K = 1024 (hi then lo)
        const short* Asrc = (kb < 16) ? Qh : Ql;
        int f0 = (kb & 15) * 32;
#pragma unroll
        for (int i = 0; i < 2; ++i) {
            int lin = tid + 256 * i;
            int row = lin >> 2, q = lin & 3;
            *(short8*)(&As[row][q * 8]) = *(const short8*)(Asrc + (size_t)(r0 + row) * NF + f0 + q * 8);
            *(short8*)(&Bs[row][q * 8]) = *(const short8*)(convb + (size_t)(l0 + row) * NF + f0 + q * 8);
        }
        __syncthreads();
        short8 af[4], bf[4];
#pragma unroll
        for (int mi = 0; mi < 4; ++mi)
            af[mi] = *(const short8*)(&As[wm * 64 + mi * 16 + lr][lg * 8]);
#pragma unroll
        for (int ni = 0; ni < 4; ++ni)
            bf[ni] = *(const short8*)(&Bs[wn * 64 + ni * 16 + lr][lg * 8]);
#pragma unroll
        for (int mi = 0; mi < 4; ++mi)
#pragma unroll
            for (int ni = 0; ni < 4; ++ni)
                acc[mi][ni] = __builtin_amdgcn_mfma_f32_16x16x32_bf16(
                    af[mi], bf[ni], acc[mi][ni], 0, 0, 0);
        __syncthreads();
    }

    int rbase = r0 + wm * 64, lbase = l0 + wn * 64;
#pragma unroll
    for (int mi = 0; mi < 4; ++mi)
#pragma unroll
        for (int ni = 0; ni < 4; ++ni)
#pragma unroll
            for (int rr = 0; rr < 4; ++rr) {
                int r = rbase + mi * 16 + lg * 4 + rr;
                int l = lbase + ni * 16 + lr;
                Gp[((size_t)b * RR + r) * LL + l] = (_Float16)acc[mi][ni][rr];
            }
}

// ---------- softmax over l per (b,r) row: f16 logits -> normalized bf16 P, in place ----------
__global__ __launch_bounds__(256) void k_softmax(_Float16* __restrict__ Gp) {
    const float LOG2E = 1.4426950408889634f;
    int row = blockIdx.x * 4 + (threadIdx.x >> 6);   // b*RR + r
    int lane = threadIdx.x & 63;
    _Float16* base = Gp + (size_t)row * LL;
    half8 hv = *(const half8*)(base + lane * 8);
    float v[8];
#pragma unroll
    for (int j = 0; j < 8; ++j) v[j] = (float)hv[j];
    float m = v[0];
#pragma unroll
    for (int j = 1; j < 8; ++j) m = fmaxf(m, v[j]);
    for (int off = 1; off < 64; off <<= 1) m = fmaxf(m, __shfl_xor(m, off));
    float s = 0.f;
    float p[8];
#pragma unroll
    for (int j = 0; j < 8; ++j) { p[j] = exp2f((v[j] - m) * LOG2E); s += p[j]; }
    for (int off = 1; off < 64; off <<= 1) s += __shfl_xor(s, off);
    float inv = 1.f / s;
    short8 o;
#pragma unroll
    for (int j = 0; j < 8; ++j) o[j] = f2b(p[j] * inv);
    *(short8*)((short*)base + lane * 8) = o;
}

// ---------- wo MFMA: out[b,f] = relu(max_r sum_l conv_fl[b,f,l]*P[b,r,l]) ----------
__global__ __launch_bounds__(256) void k_wo_mfma(
    const short* __restrict__ convfl, const short* __restrict__ P,
    float* __restrict__ out) {
    int wg = xcd_swz(blockIdx.x, 2048);
    int b = wg >> 4;
    int f0 = ((wg >> 2) & 3) * 128;   // M
    int r0 = (wg & 3) * 128;          // N
    int tid = threadIdx.x, lane = tid & 63, w = tid >> 6;
    int wm = w >> 1, wn = w & 1;
    int lr = lane & 15, lg = lane >> 4;

    __shared__ short As[128][40];
    __shared__ short Bs[128][40];

    f32x4 acc[4][4];
    for (int i = 0; i < 4; ++i)
        for (int j = 0; j < 4; ++j) acc[i][j] = (f32x4){0.f, 0.f, 0.f, 0.f};

    const short* Ab = convfl + (size_t)b * NF * LL;
    const short* Bb = P + (size_t)b * RR * LL;
    for (int kb = 0; kb < 16; ++kb) {
        int k0 = kb * 32;
#pragma unroll
        for (int i = 0; i < 2; ++i) {
            int lin = tid + 256 * i;
            int row = lin >> 2, q = lin & 3;
            *(short8*)(&As[row][q * 8]) = *(const short8*)(Ab + (size_t)(f0 + row) * LL + k0 + q * 8);
            *(short8*)(&Bs[row][q * 8]) = *(const short8*)(Bb + (size_t)(r0 + row) * LL + k0 + q * 8);
        }
        __syncthreads();
        short8 af[4], bf[4];
#pragma unroll
        for (int mi = 0; mi < 4; ++mi)
            af[mi] = *(const short8*)(&As[wm * 64 + mi * 16 + lr][lg * 8]);
#pragma unroll
        for (int ni = 0; ni < 4; ++ni)
            bf[ni] = *(const short8*)(&Bs[wn * 64 + ni * 16 + lr][lg * 8]);
#pragma unroll
        for (int mi = 0; mi < 4; ++mi)
#pragma unroll
            for (int ni = 0; ni < 4; ++ni)
                acc[mi][ni] = __builtin_amdgcn_mfma_f32_16x16x32_bf16(
                    af[mi], bf[ni], acc[mi][ni], 0, 0, 0);
        __syncthreads();
    }

    int fbase = f0 + wm * 64;
#pragma unroll
    for (int mi = 0; mi < 4; ++mi)
#pragma unroll
        for (int rr = 0; rr < 4; ++rr) {
            float m = acc[mi][0][rr];
#pragma unroll
            for (int ni = 1; ni < 4; ++ni) m = fmaxf(m, acc[mi][ni][rr]);
            m = fmaxf(m, __shfl_xor(m, 1));
            m = fmaxf(m, __shfl_xor(m, 2));
            m = fmaxf(m, __shfl_xor(m, 4));
            m = fmaxf(m, __shfl_xor(m, 8));
            if (lr == 0 && m > 0.f) {
                int f = fbase + mi * 16 + lg * 4 + rr;
                atomicMax((int*)&out[(size_t)b * NF + f], __float_as_int(m));
            }
        }
}

extern "C" void kernel_launch(void* const* d_in, const int* in_sizes, int n_in,
                              void* d_out, int out_size, void* d_ws, size_t ws_size,
                              hipStream_t stream) {
    const float* x      = (const float*)d_in[0];
    const float* e1     = (const float*)d_in[1];
    const float* e2     = (const float*)d_in[2];
    const float* posVec = (const float*)d_in[3];
    const float* We1    = (const float*)d_in[4];
    const float* We2    = (const float*)d_in[5];
    const float* U      = (const float*)d_in[6];
    const float* conv_w = (const float*)d_in[7];
    const float* conv_b = (const float*)d_in[8];
    const float* rel_w  = (const float*)d_in[9];
    float* out = (float*)d_out;

    // workspace: convlf 67MB + convfl 67MB + Gp 67MB + small = 203.4MB (< 256MiB)
    char* p = (char*)d_ws;
    short* convlf = (short*)p;  p += (size_t)BB * LL * NF * 2;
    short* convfl = (short*)p;  p += (size_t)BB * NF * LL * 2;
    _Float16* Gp  = (_Float16*)p;  p += (size_t)BB * RR * LL * 2;
    short* QhW    = (short*)p;  p += (size_t)RR * NF * 2;
    short* QlW    = (short*)p;  p += (size_t)RR * NF * 2;
    float* v1     = (float*)p;  p += (size_t)BB * DW * 4;
    float* v2     = (float*)p;  p += (size_t)BB * DW * 4;
    float* A1     = (float*)p;  p += (size_t)BB * LL * 4;
    float* A2     = (float*)p;  p += (size_t)BB * LL * 4;
    float* alpha  = (float*)p;  p += (size_t)BB * LL * 4;

    k_ve<<<BB, DW, 0, stream>>>(We1, We2, e1, e2, v1, v2);
    k_logits<<<(BB * LL) / 4, 256, 0, stream>>>(x, v1, v2, A1, A2);
    k_alpha<<<BB, LL, 0, stream>>>(A1, A2, alpha);
    k_w2t<<<dim3(NF / 64, RR / 64), 256, 0, stream>>>(U, rel_w, QhW, QlW);
    k_conv_mfma<<<2048, 256, 0, stream>>>(x, posVec, conv_w, conv_b, alpha, convlf, convfl);
    k_g_mfma<<<2048, 256, 0, stream>>>(QhW, QlW, convlf, Gp);
    k_softmax<<<(BB * RR) / 4, 256, 0, stream>>>(Gp);
    hipMemsetAsync(d_out, 0, (size_t)BB * NF * sizeof(float), stream);
    k_wo_mfma<<<2048, 256, 0, stream>>>(convfl, (const short*)Gp, out);
    hipMemcpyAsync(out + BB * NF, rel_w, (size_t)NF * RR * sizeof(float),
                   hipMemcpyDeviceToDevice, stream);
}

// Round 7
// 399.726 us; speedup vs baseline: 8.7426x; 1.2269x over previous
//
#include <hip/hip_runtime.h>
#include <hip/hip_bf16.h>

#define BB 128
#define LL 512
#define DW 256
#define DP 64
#define NF 512
#define DD 384       // D = DW + 2*DP
#define DWIN 1152    // 3*D
#define RR 512       // nr
#define LP 514       // LL + 2 pad rows

typedef __attribute__((ext_vector_type(8))) short short8;
typedef __attribute__((ext_vector_type(4))) short short4v;
typedef __attribute__((ext_vector_type(8))) _Float16 half8;
typedef __attribute__((ext_vector_type(4))) float f32x4;

typedef __attribute__((address_space(1))) const void* gas_t;
typedef __attribute__((address_space(3))) void* las_t;

__device__ __forceinline__ void stage16(const void* g, void* l) {
    __builtin_amdgcn_global_load_lds((gas_t)g, (las_t)l, 16, 0, 0);
}

__device__ inline short f2b(float v) {
    __hip_bfloat16 h = __float2bfloat16(v);
    return *reinterpret_cast<short*>(&h);
}
__device__ inline float b2f(short s) {
    unsigned u = ((unsigned)(unsigned short)s) << 16;
    return __uint_as_float(u);
}
// XCD-chunked bijective swizzle (nwg % 8 == 0)
__device__ inline int xcd_swz(int bid, int nwg) {
    return (bid & 7) * (nwg >> 3) + (bid >> 3);
}

// ---------- small kernels (fp32-exact path for alpha) ----------
__global__ void k_ve(const float* __restrict__ We1, const float* __restrict__ We2,
                     const float* __restrict__ e1, const float* __restrict__ e2,
                     float* __restrict__ v1, float* __restrict__ v2) {
    int b = blockIdx.x;
    int d = threadIdx.x; // 256
    __shared__ float s1[DW], s2[DW];
    s1[d] = e1[b * DW + d];
    s2[d] = e2[b * DW + d];
    __syncthreads();
    float a1 = 0.f, a2 = 0.f;
    for (int e = 0; e < DW; ++e) {
        a1 += We1[d * DW + e] * s1[e];
        a2 += We2[d * DW + e] * s2[e];
    }
    v1[b * DW + d] = a1;
    v2[b * DW + d] = a2;
}

__global__ __launch_bounds__(256) void k_logits(
    const float* __restrict__ x,
    const float* __restrict__ v1, const float* __restrict__ v2,
    float* __restrict__ A1, float* __restrict__ A2) {
    int row = blockIdx.x * 4 + (threadIdx.x >> 6);   // b*LL + l
    int lane = threadIdx.x & 63;
    int b = row >> 9;
    f32x4 xv = *(const f32x4*)(x + (size_t)row * DW + lane * 4);
    f32x4 w1 = *(const f32x4*)(v1 + b * DW + lane * 4);
    f32x4 w2 = *(const f32x4*)(v2 + b * DW + lane * 4);
    float p1 = xv[0] * w1[0] + xv[1] * w1[1] + xv[2] * w1[2] + xv[3] * w1[3];
    float p2 = xv[0] * w2[0] + xv[1] * w2[1] + xv[2] * w2[2] + xv[3] * w2[3];
    for (int off = 32; off; off >>= 1) {
        p1 += __shfl_down(p1, off);
        p2 += __shfl_down(p2, off);
    }
    if (lane == 0) { A1[row] = p1; A2[row] = p2; }
}

__global__ void k_alpha(const float* __restrict__ A1, const float* __restrict__ A2,
                        float* __restrict__ alpha) {
    int b = blockIdx.x;
    int l = threadIdx.x; // 512
    __shared__ float s[LL];
    float a1 = A1[b * LL + l], a2 = A2[b * LL + l];

    s[l] = a1; __syncthreads();
    for (int st = 256; st; st >>= 1) { if (l < st) s[l] = fmaxf(s[l], s[l + st]); __syncthreads(); }
    float m1 = s[0]; __syncthreads();
    float e1x = expf(a1 - m1);
    s[l] = e1x; __syncthreads();
    for (int st = 256; st; st >>= 1) { if (l < st) s[l] += s[l + st]; __syncthreads(); }
    float d1 = s[0]; __syncthreads();

    s[l] = a2; __syncthreads();
    for (int st = 256; st; st >>= 1) { if (l < st) s[l] = fmaxf(s[l], s[l + st]); __syncthreads(); }
    float m2 = s[0]; __syncthreads();
    float e2x = expf(a2 - m2);
    s[l] = e2x; __syncthreads();
    for (int st = 256; st; st >>= 1) { if (l < st) s[l] += s[l + st]; __syncthreads(); }
    float d2 = s[0];

    alpha[b * LL + l] = 0.5f * (e1x / d1 + e2x / d2);
}

// ---------- packing: px_pad[b][row][d] bf16, rows 0 and 513 zero ----------
__global__ __launch_bounds__(256) void k_pack_px(const float* __restrict__ x,
                                                 const float* __restrict__ pv,
                                                 short* __restrict__ pxp) {
    int idx = blockIdx.x * 256 + threadIdx.x;   // 128*514*48 = 3,158,016
    int d8 = (idx % 48) * 8;
    int row = (idx / 48) % LP;
    int b = idx / (48 * LP);
    short8 v = (short8){0, 0, 0, 0, 0, 0, 0, 0};
    if (row >= 1 && row <= LL) {
        int l = row - 1;
        const float* src = (d8 < DW) ? (x + ((size_t)b * LL + l) * DW + d8)
                                     : (pv + ((size_t)b * LL + l) * (2 * DP) + (d8 - DW));
        f32x4 u0 = *(const f32x4*)(src);
        f32x4 u1 = *(const f32x4*)(src + 4);
#pragma unroll
        for (int jj = 0; jj < 4; ++jj) { v[jj] = f2b(u0[jj]); v[jj + 4] = f2b(u1[jj]); }
    }
    *(short8*)(pxp + ((size_t)b * LP + row) * DD + d8) = v;
}

__global__ __launch_bounds__(256) void k_pack_w(const float* __restrict__ cw,
                                                short* __restrict__ cwb) {
    int idx = blockIdx.x * 256 + threadIdx.x;   // 512*1152/8 = 73,728
    const float* src = cw + (size_t)idx * 8;
    f32x4 u0 = *(const f32x4*)(src);
    f32x4 u1 = *(const f32x4*)(src + 4);
    short8 v;
#pragma unroll
    for (int jj = 0; jj < 4; ++jj) { v[jj] = f2b(u0[jj]); v[jj + 4] = f2b(u1[jj]); }
    *(short8*)(cwb + (size_t)idx * 8) = v;
}

// ---------- W2t[r][f] = sum_t rel_w[r,t]*U[f,t], split hi/lo bf16 ----------
__global__ void k_w2t(const float* __restrict__ U, const float* __restrict__ relw,
                      short* __restrict__ Qh, short* __restrict__ Ql) {
    __shared__ float As[16][65], Bs[16][65];
    int r0 = blockIdx.y * 64, f0 = blockIdx.x * 64;
    int tid = threadIdx.x, ty = tid >> 4, tx = tid & 15;
    float acc[4][4] = {};
    for (int k0 = 0; k0 < NF; k0 += 16) {
        for (int i = 0; i < 4; ++i) {
            int lin = tid + 256 * i;
            int kk = lin & 15, mm = lin >> 4;
            As[kk][mm] = relw[(r0 + mm) * NF + k0 + kk];
            Bs[kk][mm] = U[(f0 + mm) * NF + k0 + kk];
        }
        __syncthreads();
        for (int kk = 0; kk < 16; ++kk) {
            float av[4], bv[4];
            for (int i = 0; i < 4; ++i) av[i] = As[kk][ty * 4 + i];
            for (int j = 0; j < 4; ++j) bv[j] = Bs[kk][tx * 4 + j];
            for (int i = 0; i < 4; ++i)
                for (int j = 0; j < 4; ++j) acc[i][j] += av[i] * bv[j];
        }
        __syncthreads();
    }
    for (int i = 0; i < 4; ++i)
        for (int j = 0; j < 4; ++j) {
            float vv = acc[i][j];
            short hi = f2b(vv);
            size_t o = (size_t)(r0 + ty * 4 + i) * NF + f0 + tx * 4 + j;
            Qh[o] = hi;
            Ql[o] = f2b(vv - b2f(hi));
        }
}

// ---------- conv MFMA via global_load_lds ----------
// A[l][k] = px_pad flat row (contiguous K=1152), B[f][k] = cwb.
// Epilogue: conv_lf direct + conv_fl via LDS transpose.
__global__ __launch_bounds__(256) void k_conv_mfma(
    const short* __restrict__ pxp, const short* __restrict__ cwb,
    const float* __restrict__ conv_b, const float* __restrict__ alpha,
    short* __restrict__ conv_lf, short* __restrict__ conv_fl) {
    int wg = xcd_swz(blockIdx.x, 2048);
    int b = wg >> 4;
    int l0 = ((wg >> 2) & 3) * 128;
    int f0 = (wg & 3) * 128;
    int tid = threadIdx.x;
    int lane = tid & 63, w = tid >> 6;
    int wm = w >> 1, wn = w & 1;
    int lr = lane & 15, lg = lane >> 4;

    // union: K-loop As/Bs (2*8192B linear); epilogue T[128][136] (34816B)
    __shared__ __align__(16) char smem[34816];
    short (*As)[32] = (short(*)[32])smem;
    short (*Bs)[32] = (short(*)[32])(smem + 8192);
    short (*T)[136] = (short(*)[136])smem;

    f32x4 acc[4][4];
    for (int i = 0; i < 4; ++i)
        for (int j = 0; j < 4; ++j) acc[i][j] = (f32x4){0.f, 0.f, 0.f, 0.f};

    // staging geometry: wave w stages rows [w*32, w*32+32), 16 rows per call
    int rowA = lane >> 2;               // 0..15
    int sw = (lane & 3) ^ (rowA & 3);   // pre-swizzled source slot
    const short* gA = pxp + ((size_t)b * LP + l0 + w * 32 + rowA) * DD + sw * 8;
    const short* gB = cwb + (size_t)(f0 + w * 32 + rowA) * DWIN + sw * 8;
    short* lA = &As[w * 32][0];
    short* lB = &Bs[w * 32][0];
    int rsw = (lg ^ (lr & 3)) * 8;      // read-side swizzled slot offset

    for (int kb = 0; kb < 36; ++kb) {
        int k0 = kb * 32;
        stage16(gA + k0, lA);
        stage16(gA + 16 * DD + k0, lA + 16 * 32);
        stage16(gB + k0, lB);
        stage16(gB + (size_t)16 * DWIN + k0, lB + 16 * 32);
        __syncthreads();
        short8 af[4], bf[4];
#pragma unroll
        for (int mi = 0; mi < 4; ++mi)
            af[mi] = *(const short8*)(&As[wm * 64 + mi * 16 + lr][rsw]);
#pragma unroll
        for (int ni = 0; ni < 4; ++ni)
            bf[ni] = *(const short8*)(&Bs[wn * 64 + ni * 16 + lr][rsw]);
#pragma unroll
        for (int mi = 0; mi < 4; ++mi)
#pragma unroll
            for (int ni = 0; ni < 4; ++ni)
                acc[mi][ni] = __builtin_amdgcn_mfma_f32_16x16x32_bf16(
                    af[mi], bf[ni], acc[mi][ni], 0, 0, 0);
        __syncthreads();
    }

    int lbase = l0 + wm * 64, fbase = f0 + wn * 64;
#pragma unroll
    for (int mi = 0; mi < 4; ++mi) {
        f32x4 av = *(const f32x4*)(alpha + (size_t)b * LL + lbase + mi * 16 + lg * 4);
        int lrow = lbase + mi * 16 + lg * 4;
#pragma unroll
        for (int ni = 0; ni < 4; ++ni) {
            int f = fbase + ni * 16 + lr;
            float bias = conv_b[f];
            short4v o;
#pragma unroll
            for (int r = 0; r < 4; ++r) {
                float val = tanhf(av[r] * acc[mi][ni][r] + bias);
                short sv = f2b(val);
                o[r] = sv;
                conv_lf[((size_t)b * LL + lrow + r) * NF + f] = sv;
            }
            *(short4v*)(&T[wn * 64 + ni * 16 + lr][wm * 64 + mi * 16 + lg * 4]) = o;
        }
    }
    __syncthreads();
#pragma unroll
    for (int i = 0; i < 8; ++i) {
        int lin = tid + 256 * i;
        int frow = lin >> 4;
        int q = lin & 15;
        short8 v = *(const short8*)(&T[frow][q * 8]);
        *(short8*)(conv_fl + ((size_t)b * NF + f0 + frow) * LL + l0 + q * 8) = v;
    }
}

// ---------- G MFMA: Gp[b][r][l] = sum_f (Qh+Ql)[r,f]*conv_lf[b,l,f], f16 out ----------
__global__ __launch_bounds__(256) void k_g_mfma(
    const short* __restrict__ Qh, const short* __restrict__ Ql,
    const short* __restrict__ convlf, _Float16* __restrict__ Gp) {
    int wg = xcd_swz(blockIdx.x, 2048);
    int b = wg >> 4;
    int r0 = ((wg >> 2) & 3) * 128;   // M
    int l0 = (wg & 3) * 128;          // N
    int tid = threadIdx.x, lane = tid & 63, w = tid >> 6;
    int wm = w >> 1, wn = w & 1;
    int lr = lane & 15, lg = lane >> 4;

    __shared__ __align__(16) short As[128][32];
    __shared__ __align__(16) short Bs[128][32];

    f32x4 acc[4][4];
    for (int i = 0; i < 4; ++i)
        for (int j = 0; j < 4; ++j) acc[i][j] = (f32x4){0.f, 0.f, 0.f, 0.f};

    int rowA = lane >> 2;
    int sw = (lane & 3) ^ (rowA & 3);
    size_t aoff = (size_t)(r0 + w * 32 + rowA) * NF + sw * 8;
    const short* gB = convlf + (size_t)b * LL * NF + (size_t)(l0 + w * 32 + rowA) * NF + sw * 8;
    short* lA = &As[w * 32][0];
    short* lB = &Bs[w * 32][0];
    int rsw = (lg ^ (lr & 3)) * 8;

    for (int kb = 0; kb < 32; ++kb) {            // virtual K = 1024 (hi then lo)
        const short* gA = ((kb < 16) ? Qh : Ql) + aoff;
        int f0k = (kb & 15) * 32;
        stage16(gA + f0k, lA);
        stage16(gA + 16 * NF + f0k, lA + 16 * 32);
        stage16(gB + f0k, lB);
        stage16(gB + 16 * NF + f0k, lB + 16 * 32);
        __syncthreads();
        short8 af[4], bf[4];
#pragma unroll
        for (int mi = 0; mi < 4; ++mi)
            af[mi] = *(const short8*)(&As[wm * 64 + mi * 16 + lr][rsw]);
#pragma unroll
        for (int ni = 0; ni < 4; ++ni)
            bf[ni] = *(const short8*)(&Bs[wn * 64 + ni * 16 + lr][rsw]);
#pragma unroll
        for (int mi = 0; mi < 4; ++mi)
#pragma unroll
            for (int ni = 0; ni < 4; ++ni)
                acc[mi][ni] = __builtin_amdgcn_mfma_f32_16x16x32_bf16(
                    af[mi], bf[ni], acc[mi][ni], 0, 0, 0);
        __syncthreads();
    }

    int rbase = r0 + wm * 64, lbase = l0 + wn * 64;
#pragma unroll
    for (int mi = 0; mi < 4; ++mi)
#pragma unroll
        for (int ni = 0; ni < 4; ++ni)
#pragma unroll
            for (int rr = 0; rr < 4; ++rr) {
                int r = rbase + mi * 16 + lg * 4 + rr;
                int l = lbase + ni * 16 + lr;
                Gp[((size_t)b * RR + r) * LL + l] = (_Float16)acc[mi][ni][rr];
            }
}

// ---------- softmax over l per (b,r) row: f16 logits -> normalized bf16 P, in place ----------
__global__ __launch_bounds__(256) void k_softmax(_Float16* __restrict__ Gp) {
    const float LOG2E = 1.4426950408889634f;
    int row = blockIdx.x * 4 + (threadIdx.x >> 6);   // b*RR + r
    int lane = threadIdx.x & 63;
    _Float16* base = Gp + (size_t)row * LL;
    half8 hv = *(const half8*)(base + lane * 8);
    float v[8];
#pragma unroll
    for (int j = 0; j < 8; ++j) v[j] = (float)hv[j];
    float m = v[0];
#pragma unroll
    for (int j = 1; j < 8; ++j) m = fmaxf(m, v[j]);
    for (int off = 1; off < 64; off <<= 1) m = fmaxf(m, __shfl_xor(m, off));
    float s = 0.f;
    float p[8];
#pragma unroll
    for (int j = 0; j < 8; ++j) { p[j] = exp2f((v[j] - m) * LOG2E); s += p[j]; }
    for (int off = 1; off < 64; off <<= 1) s += __shfl_xor(s, off);
    float inv = 1.f / s;
    short8 o;
#pragma unroll
    for (int j = 0; j < 8; ++j) o[j] = f2b(p[j] * inv);
    *(short8*)((short*)base + lane * 8) = o;
}

// ---------- wo MFMA: out[b,f] = relu(max_r sum_l conv_fl[b,f,l]*P[b,r,l]) ----------
__global__ __launch_bounds__(256) void k_wo_mfma(
    const short* __restrict__ convfl, const short* __restrict__ P,
    float* __restrict__ out) {
    int wg = xcd_swz(blockIdx.x, 2048);
    int b = wg >> 4;
    int f0 = ((wg >> 2) & 3) * 128;   // M
    int r0 = (wg & 3) * 128;          // N
    int tid = threadIdx.x, lane = tid & 63, w = tid >> 6;
    int wm = w >> 1, wn = w & 1;
    int lr = lane & 15, lg = lane >> 4;

    __shared__ __align__(16) short As[128][32];
    __shared__ __align__(16) short Bs[128][32];

    f32x4 acc[4][4];
    for (int i = 0; i < 4; ++i)
        for (int j = 0; j < 4; ++j) acc[i][j] = (f32x4){0.f, 0.f, 0.f, 0.f};

    int rowA = lane >> 2;
    int sw = (lane & 3) ^ (rowA & 3);
    const short* gA = convfl + (size_t)b * NF * LL + (size_t)(f0 + w * 32 + rowA) * LL + sw * 8;
    const short* gB = P + (size_t)b * RR * LL + (size_t)(r0 + w * 32 + rowA) * LL + sw * 8;
    short* lA = &As[w * 32][0];
    short* lB = &Bs[w * 32][0];
    int rsw = (lg ^ (lr & 3)) * 8;

    for (int kb = 0; kb < 16; ++kb) {
        int k0 = kb * 32;
        stage16(gA + k0, lA);
        stage16(gA + 16 * LL + k0, lA + 16 * 32);
        stage16(gB + k0, lB);
        stage16(gB + 16 * LL + k0, lB + 16 * 32);
        __syncthreads();
        short8 af[4], bf[4];
#pragma unroll
        for (int mi = 0; mi < 4; ++mi)
            af[mi] = *(const short8*)(&As[wm * 64 + mi * 16 + lr][rsw]);
#pragma unroll
        for (int ni = 0; ni < 4; ++ni)
            bf[ni] = *(const short8*)(&Bs[wn * 64 + ni * 16 + lr][rsw]);
#pragma unroll
        for (int mi = 0; mi < 4; ++mi)
#pragma unroll
            for (int ni = 0; ni < 4; ++ni)
                acc[mi][ni] = __builtin_amdgcn_mfma_f32_16x16x32_bf16(
                    af[mi], bf[ni], acc[mi][ni], 0, 0, 0);
        __syncthreads();
    }

    int fbase = f0 + wm * 64;
#pragma unroll
    for (int mi = 0; mi < 4; ++mi)
#pragma unroll
        for (int rr = 0; rr < 4; ++rr) {
            float m = acc[mi][0][rr];
#pragma unroll
            for (int ni = 1; ni < 4; ++ni) m = fmaxf(m, acc[mi][ni][rr]);
            m = fmaxf(m, __shfl_xor(m, 1));
            m = fmaxf(m, __shfl_xor(m, 2));
            m = fmaxf(m, __shfl_xor(m, 4));
            m = fmaxf(m, __shfl_xor(m, 8));
            if (lr == 0 && m > 0.f) {
                int f = fbase + mi * 16 + lg * 4 + rr;
                atomicMax((int*)&out[(size_t)b * NF + f], __float_as_int(m));
            }
        }
}

extern "C" void kernel_launch(void* const* d_in, const int* in_sizes, int n_in,
                              void* d_out, int out_size, void* d_ws, size_t ws_size,
                              hipStream_t stream) {
    const float* x      = (const float*)d_in[0];
    const float* e1     = (const float*)d_in[1];
    const float* e2     = (const float*)d_in[2];
    const float* posVec = (const float*)d_in[3];
    const float* We1    = (const float*)d_in[4];
    const float* We2    = (const float*)d_in[5];
    const float* U      = (const float*)d_in[6];
    const float* conv_w = (const float*)d_in[7];
    const float* conv_b = (const float*)d_in[8];
    const float* rel_w  = (const float*)d_in[9];
    float* out = (float*)d_out;

    // workspace (bytes):
    //   convlf 67,108,864 | convfl 67,108,864 | Gp 67,108,864
    //   pxp 128*514*384*2 = 50,528,256 | cwb 1,179,648 | Qh+Ql 1,048,576
    //   v1,v2 262,144 | A1,A2,alpha 786,432   -> total 255,131,648 (< 256 MiB)
    char* p = (char*)d_ws;
    short* convlf = (short*)p;  p += (size_t)BB * LL * NF * 2;
    short* convfl = (short*)p;  p += (size_t)BB * NF * LL * 2;
    _Float16* Gp  = (_Float16*)p;  p += (size_t)BB * RR * LL * 2;
    short* pxp    = (short*)p;  p += (size_t)BB * LP * DD * 2;
    short* cwb    = (short*)p;  p += (size_t)NF * DWIN * 2;
    short* QhW    = (short*)p;  p += (size_t)RR * NF * 2;
    short* QlW    = (short*)p;  p += (size_t)RR * NF * 2;
    float* v1     = (float*)p;  p += (size_t)BB * DW * 4;
    float* v2     = (float*)p;  p += (size_t)BB * DW * 4;
    float* A1     = (float*)p;  p += (size_t)BB * LL * 4;
    float* A2     = (float*)p;  p += (size_t)BB * LL * 4;
    float* alpha  = (float*)p;  p += (size_t)BB * LL * 4;

    k_pack_px<<<(BB * LP * 48) / 256, 256, 0, stream>>>(x, posVec, pxp);
    k_pack_w<<<(NF * DWIN / 8) / 256, 256, 0, stream>>>(conv_w, cwb);
    k_ve<<<BB, DW, 0, stream>>>(We1, We2, e1, e2, v1, v2);
    k_logits<<<(BB * LL) / 4, 256, 0, stream>>>(x, v1, v2, A1, A2);
    k_alpha<<<BB, LL, 0, stream>>>(A1, A2, alpha);
    k_w2t<<<dim3(NF / 64, RR / 64), 256, 0, stream>>>(U, rel_w, QhW, QlW);
    k_conv_mfma<<<2048, 256, 0, stream>>>(pxp, cwb, conv_b, alpha, convlf, convfl);
    k_g_mfma<<<2048, 256, 0, stream>>>(QhW, QlW, convlf, Gp);
    k_softmax<<<(BB * RR) / 4, 256, 0, stream>>>(Gp);
    hipMemsetAsync(d_out, 0, (size_t)BB * NF * sizeof(float), stream);
    k_wo_mfma<<<2048, 256, 0, stream>>>(convfl, (const short*)Gp, out);
    hipMemcpyAsync(out + BB * NF, rel_w, (size_t)NF * RR * sizeof(float),
                   hipMemcpyDeviceToDevice, stream);
}